// Round 2
// baseline (2294.725 us; speedup 1.0000x reference)
//
#include <hip/hip_runtime.h>
#include <stdint.h>

typedef unsigned short u16;
typedef __bf16 bf16x8 __attribute__((ext_vector_type(8)));
typedef float f32x4 __attribute__((ext_vector_type(4)));

#define DEVINL __device__ __forceinline__

DEVINL u16 f2bf(float f) {
  union { float f; unsigned u; } c; c.f = f;
  unsigned u = c.u + 0x7FFFu + ((c.u >> 16) & 1u);
  return (u16)(u >> 16);
}

DEVINL void gl2lds16(const void* g, void* l) {
  __builtin_amdgcn_global_load_lds(
      (const __attribute__((address_space(1))) unsigned int*)g,
      (__attribute__((address_space(3))) unsigned int*)l, 16, 0, 0);
}

// ---------------- fp32 -> bf16 weight conversion ----------------
__global__ __launch_bounds__(256) void cvt_kernel(const float* __restrict__ src,
                                                  u16* __restrict__ dst, int n4) {
  int i = blockIdx.x * 256 + threadIdx.x;
  if (i >= n4) return;
  float4 v = ((const float4*)src)[i];
  unsigned a = (unsigned)f2bf(v.x) | ((unsigned)f2bf(v.y) << 16);
  unsigned b = (unsigned)f2bf(v.z) | ((unsigned)f2bf(v.w) << 16);
  ((uint2*)dst)[i] = make_uint2(a, b);
}

// in_W (768x54) -> bf16 (768x64) zero-padded K
__global__ __launch_bounds__(256) void pad_inw_kernel(const float* __restrict__ src,
                                                      u16* __restrict__ dst) {
  int t = blockIdx.x * 256 + threadIdx.x;  // 768*64
  int r = t >> 6, c = t & 63;
  dst[t] = (c < 54) ? f2bf(src[r * 54 + c]) : (u16)0;
}

// ---------------- fourier embed: (Mc,3)+(Mc,3) -> bf16 (Mc x 64) ----------------
__global__ __launch_bounds__(256) void embed_kernel(const float* __restrict__ pc,
                                                    const float* __restrict__ feats,
                                                    u16* __restrict__ emb) {
  int t = blockIdx.x * 256 + threadIdx.x;
  int p = t >> 6, c = t & 63;
  float v = 0.f;
  if (c < 3) {
    v = pc[p * 3 + c];
  } else if (c < 27) {
    int i = c - 3;
    float f = (float)(1 << (i & 7));
    v = sinf(pc[p * 3 + (i >> 3)] * f);
  } else if (c < 51) {
    int i = c - 27;
    float f = (float)(1 << (i & 7));
    v = cosf(pc[p * 3 + (i >> 3)] * f);
  } else if (c < 54) {
    v = feats[p * 3 + (c - 51)];
  }
  emb[t] = f2bf(v);
}

// ---------------- generic GEMM: C(MxN) = A(MxK,bf16) * Bw(NxK,bf16)^T + bias ----------------
__global__ __launch_bounds__(256) void gemm_kernel(
    const u16* __restrict__ A, const u16* __restrict__ Bw,
    const float* __restrict__ bias, const float* __restrict__ resid,
    float* __restrict__ outF, u16* __restrict__ outB,
    int M, int N, int K, int gelu) {
  __shared__ u16 As[128 * 32];
  __shared__ u16 Bs[128 * 32];
  const int tid = threadIdx.x;
  const int lane = tid & 63, w = tid >> 6;
  const int l15 = lane & 15, quad = lane >> 4;
  const int mblk = blockIdx.x * 128, nblk = blockIdx.y * 128;
  const int wm = (w & 1) * 64, wn = (w >> 1) * 64;

  f32x4 zero = {0.f, 0.f, 0.f, 0.f};
  f32x4 acc[4][4];
#pragma unroll
  for (int i = 0; i < 4; i++)
#pragma unroll
    for (int j = 0; j < 4; j++) acc[i][j] = zero;

  for (int k0 = 0; k0 < K; k0 += 32) {
#pragma unroll
    for (int p = 0; p < 2; ++p) {
      int slot = tid + p * 256;  // 512 slots of 16B per 8KB tile
      int row = slot >> 2, c8 = (slot & 3) << 3;
      gl2lds16(A + (size_t)(mblk + row) * K + (k0 + c8), &As[slot * 8]);
      gl2lds16(Bw + (size_t)(nblk + row) * K + (k0 + c8), &Bs[slot * 8]);
    }
    __syncthreads();
    bf16x8 af[4], bf[4];
#pragma unroll
    for (int i = 0; i < 4; i++)
      af[i] = *(const bf16x8*)&As[(wm + i * 16 + l15) * 32 + quad * 8];
#pragma unroll
    for (int j = 0; j < 4; j++)
      bf[j] = *(const bf16x8*)&Bs[(wn + j * 16 + l15) * 32 + quad * 8];
#pragma unroll
    for (int i = 0; i < 4; i++)
#pragma unroll
      for (int j = 0; j < 4; j++)
        acc[i][j] = __builtin_amdgcn_mfma_f32_16x16x32_bf16(af[i], bf[j], acc[i][j], 0, 0, 0);
    __syncthreads();
  }

#pragma unroll
  for (int i = 0; i < 4; i++) {
    int row0 = mblk + wm + i * 16 + quad * 4;
#pragma unroll
    for (int j = 0; j < 4; j++) {
      int col = nblk + wn + j * 16 + l15;
      float bv = bias[col];
#pragma unroll
      for (int r = 0; r < 4; r++) {
        float v = acc[i][j][r] + bv;
        if (gelu) v = 0.5f * v * (1.0f + erff(v * 0.70710678118f));
        size_t idx = (size_t)(row0 + r) * N + col;
        if (resid) v += resid[idx];
        if (outF) outF[idx] = v;
        if (outB) outB[idx] = f2bf(v);
      }
    }
  }
}

// ---------------- V^T repack: In rows (s,d per head) -> Vt[(b*12+h)*64 + d][Skv] ----------------
__global__ __launch_bounds__(256) void repack_vt_kernel(
    const u16* __restrict__ In, long bstride, int rs, int voff, int hs,
    u16* __restrict__ Vt, int Skv) {
  __shared__ u16 tile[64 * 65];
  int nst = Skv >> 6;
  int bid = blockIdx.x;
  int st = bid % nst;
  int bh = bid / nst;
  int h = bh % 12, b = bh / 12;
  const u16* src = In + (size_t)b * bstride + (size_t)(st * 64) * rs + voff + h * hs;
  int tid = threadIdx.x;
#pragma unroll
  for (int p = 0; p < 2; p++) {
    int slot = tid + p * 256;  // s = slot>>3 (64 rows), d8 = (slot&7)*8
    int s = slot >> 3, d8 = (slot & 7) << 3;
    uint4 v = *(const uint4*)(src + (size_t)s * rs + d8);
    u16 tmp[8];
    *(uint4*)tmp = v;
#pragma unroll
    for (int j = 0; j < 8; j++) tile[s * 65 + d8 + j] = tmp[j];
  }
  __syncthreads();
  u16* dst = Vt + ((size_t)(b * 12 + h) * 64) * Skv + st * 64;
#pragma unroll
  for (int p = 0; p < 2; p++) {
    int slot = tid + p * 256;  // d = slot>>3, s8 = (slot&7)*8
    int d = slot >> 3, s8 = (slot & 7) << 3;
    u16 tmp[8];
#pragma unroll
    for (int j = 0; j < 8; j++) tmp[j] = tile[(s8 + j) * 65 + d];
    *(uint4*)(dst + (size_t)d * Skv + s8) = *(uint4*)tmp;
  }
}

// ---------------- flash attention (MFMA, online softmax) ----------------
__global__ __launch_bounds__(256) void flash_kernel(
    const u16* __restrict__ Q, long qb, int qrs, int qhs,
    const u16* __restrict__ Kp, long kb, int krs, int khs,
    const u16* __restrict__ Vt, u16* __restrict__ Out,
    int Skv, float scale2) {
  __shared__ u16 Qs[64 * 64];
  __shared__ u16 Ks[64 * 64];
  __shared__ u16 Vs[64 * 64];
  __shared__ u16 Ps[64 * 72];

  const int tid = threadIdx.x;
  const int lane = tid & 63, w = tid >> 6;
  const int l15 = lane & 15, quad = lane >> 4;

  int bid = blockIdx.x;  // CB*H*4
  int qt = bid & 3, bh = bid >> 2;
  int h = bh % 12, b = bh / 12;

  const u16* Qbase = Q + (size_t)b * qb + (size_t)(qt * 64) * qrs + h * qhs;
  const u16* Kbase = Kp + (size_t)b * kb + (size_t)h * khs;
  const u16* Vbase = Vt + ((size_t)(b * 12 + h) * 64) * Skv;

#pragma unroll
  for (int p = 0; p < 2; ++p) {
    int slot = tid + p * 256;
    int row = slot >> 3, c8 = (slot & 7) << 3;
    gl2lds16(Qbase + (size_t)row * qrs + c8, &Qs[slot * 8]);
  }
  __syncthreads();

  bf16x8 qa[2];
#pragma unroll
  for (int kk = 0; kk < 2; kk++)
    qa[kk] = *(const bf16x8*)&Qs[(w * 16 + l15) * 64 + kk * 32 + quad * 8];

  f32x4 zero = {0.f, 0.f, 0.f, 0.f};
  f32x4 O[4];
  float m_i[4], l_i[4];
#pragma unroll
  for (int d = 0; d < 4; d++) O[d] = zero;
#pragma unroll
  for (int r = 0; r < 4; r++) { m_i[r] = -1e30f; l_i[r] = 0.f; }

  for (int kt = 0; kt < Skv; kt += 64) {
#pragma unroll
    for (int p = 0; p < 2; ++p) {
      int slot = tid + p * 256;
      int row = slot >> 3, c8 = (slot & 7) << 3;
      gl2lds16(Kbase + (size_t)(kt + row) * krs + c8, &Ks[slot * 8]);
      gl2lds16(Vbase + (size_t)row * Skv + kt + c8, &Vs[slot * 8]);
    }
    __syncthreads();

    f32x4 S[4];
#pragma unroll
    for (int j = 0; j < 4; j++) S[j] = zero;
#pragma unroll
    for (int kk = 0; kk < 2; kk++) {
#pragma unroll
      for (int j = 0; j < 4; j++) {
        bf16x8 kf = *(const bf16x8*)&Ks[(j * 16 + l15) * 64 + kk * 32 + quad * 8];
        S[j] = __builtin_amdgcn_mfma_f32_16x16x32_bf16(qa[kk], kf, S[j], 0, 0, 0);
      }
    }
    float alpha[4];
#pragma unroll
    for (int r = 0; r < 4; r++) {
      float s0 = S[0][r] * scale2, s1 = S[1][r] * scale2;
      float s2 = S[2][r] * scale2, s3 = S[3][r] * scale2;
      S[0][r] = s0; S[1][r] = s1; S[2][r] = s2; S[3][r] = s3;
      float mx = fmaxf(fmaxf(s0, s1), fmaxf(s2, s3));
#pragma unroll
      for (int msk = 1; msk < 16; msk <<= 1) mx = fmaxf(mx, __shfl_xor(mx, msk, 64));
      float mnew = fmaxf(m_i[r], mx);
      float al = __expf(m_i[r] - mnew);
      m_i[r] = mnew;
      alpha[r] = al;
      float sum = 0.f;
#pragma unroll
      for (int j = 0; j < 4; j++) {
        float pv = __expf(S[j][r] - mnew);
        S[j][r] = pv;
        sum += pv;
      }
#pragma unroll
      for (int msk = 1; msk < 16; msk <<= 1) sum += __shfl_xor(sum, msk, 64);
      l_i[r] = l_i[r] * al + sum;
    }
    // P -> LDS (wave-private rows), C-layout -> A-layout transform
#pragma unroll
    for (int j = 0; j < 4; j++)
#pragma unroll
      for (int r = 0; r < 4; r++)
        Ps[(w * 16 + quad * 4 + r) * 72 + j * 16 + l15] = f2bf(S[j][r]);
#pragma unroll
    for (int d = 0; d < 4; d++)
#pragma unroll
      for (int r = 0; r < 4; r++) O[d][r] *= alpha[r];
    __asm__ __volatile__("s_waitcnt lgkmcnt(0)" ::: "memory");
#pragma unroll
    for (int kk = 0; kk < 2; kk++) {
      bf16x8 pa = *(const bf16x8*)&Ps[(w * 16 + l15) * 72 + kk * 32 + quad * 8];
#pragma unroll
      for (int d = 0; d < 4; d++) {
        bf16x8 vf = *(const bf16x8*)&Vs[(d * 16 + l15) * 64 + kk * 32 + quad * 8];
        O[d] = __builtin_amdgcn_mfma_f32_16x16x32_bf16(pa, vf, O[d], 0, 0, 0);
      }
    }
    __syncthreads();
  }

  u16* Ob = Out + ((size_t)(b * 256 + qt * 64 + w * 16 + quad * 4)) * 768 + h * 64 + l15;
#pragma unroll
  for (int d = 0; d < 4; d++)
#pragma unroll
    for (int r = 0; r < 4; r++) {
      float v = O[d][r] / l_i[r];
      Ob[(size_t)r * 768 + d * 16] = f2bf(v);
    }
}

// ---------------- LayerNorm: fp32 (2048x768) -> bf16 with scale/bias ----------------
__global__ __launch_bounds__(256) void ln_kernel(const float* __restrict__ X,
                                                 const float* __restrict__ sc,
                                                 const float* __restrict__ bi,
                                                 u16* __restrict__ Hout) {
  int row = blockIdx.x;
  int tid = threadIdx.x;
  const float* x = X + (size_t)row * 768;
  float v0 = x[tid], v1 = x[tid + 256], v2 = x[tid + 512];
  float s = v0 + v1 + v2;
  float q = v0 * v0 + v1 * v1 + v2 * v2;
#pragma unroll
  for (int m = 1; m < 64; m <<= 1) {
    s += __shfl_xor(s, m, 64);
    q += __shfl_xor(q, m, 64);
  }
  __shared__ float rs[4], rq[4];
  if ((tid & 63) == 0) { rs[tid >> 6] = s; rq[tid >> 6] = q; }
  __syncthreads();
  s = rs[0] + rs[1] + rs[2] + rs[3];
  q = rq[0] + rq[1] + rq[2] + rq[3];
  float mu = s * (1.f / 768.f);
  float var = q * (1.f / 768.f) - mu * mu;
  float rstd = rsqrtf(var + 1e-5f);
  u16* ho = Hout + (size_t)row * 768;
  ho[tid]       = f2bf((v0 - mu) * rstd * sc[tid]       + bi[tid]);
  ho[tid + 256] = f2bf((v1 - mu) * rstd * sc[tid + 256] + bi[tid + 256]);
  ho[tid + 512] = f2bf((v2 - mu) * rstd * sc[tid + 512] + bi[tid + 512]);
}

__global__ __launch_bounds__(256) void copy4_kernel(const float* __restrict__ src,
                                                    float* __restrict__ dst, int n4) {
  int i = blockIdx.x * 256 + threadIdx.x;
  if (i < n4) ((float4*)dst)[i] = ((const float4*)src)[i];
}

// =====================================================================
extern "C" void kernel_launch(void* const* d_in, const int* in_sizes, int n_in,
                              void* d_out, int out_size, void* d_ws, size_t ws_size,
                              hipStream_t stream) {
  const float* pc        = (const float*)d_in[0];
  const float* feats     = (const float*)d_in[1];
  const float* query     = (const float*)d_in[2];
  const float* in_W      = (const float*)d_in[3];
  const float* in_b      = (const float*)d_in[4];
  const float* ca_qkv_W  = (const float*)d_in[5];
  const float* ca_qkv_b  = (const float*)d_in[6];
  const float* ca_proj_W = (const float*)d_in[7];
  const float* ca_proj_b = (const float*)d_in[8];
  const float* ln1_s     = (const float*)d_in[9];
  const float* ln1_b     = (const float*)d_in[10];
  const float* qkv_W     = (const float*)d_in[11];
  const float* qkv_b     = (const float*)d_in[12];
  const float* proj_W    = (const float*)d_in[13];
  const float* proj_b    = (const float*)d_in[14];
  const float* ln2_s     = (const float*)d_in[15];
  const float* ln2_b     = (const float*)d_in[16];
  const float* fc_W      = (const float*)d_in[17];
  const float* fc_b      = (const float*)d_in[18];
  const float* fc2_W     = (const float*)d_in[19];
  const float* fc2_b     = (const float*)d_in[20];

  char* base = (char*)d_ws;
  size_t off = 0;
  auto alloc = [&](size_t bytes) -> char* {
    char* p = base + off;
    off += (bytes + 255) & ~(size_t)255;
    return p;
  };

  // ---- fixed region (~37 MB) ----
  u16* Wq      = (u16*)alloc(768 * 64 * 2);
  u16* Wquery  = (u16*)alloc(256 * 768 * 2);
  u16* Wcaqkv  = (u16*)alloc(2304 * 768 * 2);
  u16* Wcaproj = (u16*)alloc(768 * 768 * 2);
  u16* Wlqkv   = (u16*)alloc(2304 * 768 * 2);   // per-layer rotating
  u16* Wlproj  = (u16*)alloc(768 * 768 * 2);
  u16* Wlfc    = (u16*)alloc(3072 * 768 * 2);
  u16* Wlfc2   = (u16*)alloc(768 * 3072 * 2);
  u16* qc      = (u16*)alloc(256 * 768 * 2);
  u16* attn    = (u16*)alloc((size_t)2048 * 768 * 2);
  u16* hbuf    = (u16*)alloc((size_t)2048 * 768 * 2);
  char* uni    = alloc(12582912);               // union: (qkvb 9.4MB + VtS 3.1MB) | fc1 12.6MB
  u16* qkvb    = (u16*)uni;
  u16* VtS     = (u16*)(uni + 9437184);
  u16* fc1     = (u16*)uni;

  // ---- adaptive cross-attn chunking by ws budget ----
  size_t fixed_end = off;
  size_t per_b = (size_t)4096 * 64 * 2 + (size_t)4096 * 768 * 2 + (size_t)4096 * 1536 * 2;
  int CB;
  if (fixed_end + 8 * per_b + 4096 <= ws_size) CB = 8;
  else if (fixed_end + 2 * per_b + 4096 <= ws_size) CB = 2;
  else CB = 1;

  u16* emb   = (u16*)alloc((size_t)CB * 4096 * 64 * 2);
  u16* dataB = (u16*)alloc((size_t)CB * 4096 * 768 * 2);
  u16* kvb   = (u16*)alloc((size_t)CB * 4096 * 1536 * 2);
  u16* VtC   = dataB;  // alias: data dead before repack writes VtC

  float* latents = (float*)d_out;  // (2048 x 768) fp32
  const float scale2 = 0.125f;     // SCALE^2 = 1/sqrt(D_HEAD)

  auto cvt = [&](const float* s, u16* d, size_t n) {
    int n4 = (int)(n / 4);
    cvt_kernel<<<(n4 + 255) / 256, 256, 0, stream>>>(s, d, n4);
  };

  // --- upfront conversions (cross-attn weights only) ---
  cvt(query, Wquery, 256 * 768);
  cvt(ca_qkv_W, Wcaqkv, 2304 * 768);
  cvt(ca_proj_W, Wcaproj, 768 * 768);
  pad_inw_kernel<<<192, 256, 0, stream>>>(in_W, Wq);

  // --- latent q projection (batch-independent) ---
  gemm_kernel<<<dim3(2, 6), 256, 0, stream>>>(Wquery, Wcaqkv, ca_qkv_b, nullptr, nullptr, qc,
                                              256, 768, 768, 0);

  // --- cross-attention, chunked over batches ---
  int nchunk = 8 / CB;
  for (int c = 0; c < nchunk; ++c) {
    int Mc = CB * 4096;
    const float* pc_c = pc + (size_t)c * Mc * 3;
    const float* ft_c = feats + (size_t)c * Mc * 3;
    embed_kernel<<<Mc / 4, 256, 0, stream>>>(pc_c, ft_c, emb);
    gemm_kernel<<<dim3(Mc / 128, 6), 256, 0, stream>>>(emb, Wq, in_b, nullptr, nullptr, dataB,
                                                       Mc, 768, 64, 0);
    gemm_kernel<<<dim3(Mc / 128, 12), 256, 0, stream>>>(dataB, Wcaqkv + (size_t)768 * 768,
                                                        ca_qkv_b + 768, nullptr, nullptr, kvb,
                                                        Mc, 1536, 768, 0);
    repack_vt_kernel<<<CB * 12 * 64, 256, 0, stream>>>(kvb, (long)4096 * 1536, 1536, 768, 64,
                                                       VtC, 4096);
    flash_kernel<<<CB * 48, 256, 0, stream>>>(qc, 0L, 768, 64,
                                              kvb, (long)4096 * 1536, 1536, 64,
                                              VtC, attn + (size_t)c * CB * 256 * 768,
                                              4096, scale2);
  }
  gemm_kernel<<<dim3(16, 6), 256, 0, stream>>>(attn, Wcaproj, ca_proj_b, nullptr, latents,
                                               nullptr, 2048, 768, 768, 0);

  // --- transformer layers (weights converted per layer into rotating buffers) ---
  for (int l = 0; l < 8; ++l) {
    cvt(qkv_W + (size_t)l * 2304 * 768, Wlqkv, 2304 * 768);
    cvt(proj_W + (size_t)l * 768 * 768, Wlproj, 768 * 768);
    cvt(fc_W + (size_t)l * 3072 * 768, Wlfc, 3072 * 768);
    cvt(fc2_W + (size_t)l * 768 * 3072, Wlfc2, 768 * 3072);

    ln_kernel<<<2048, 256, 0, stream>>>(latents, ln1_s + l * 768, ln1_b + l * 768, hbuf);
    gemm_kernel<<<dim3(16, 18), 256, 0, stream>>>(hbuf, Wlqkv, qkv_b + l * 2304,
                                                  nullptr, nullptr, qkvb, 2048, 2304, 768, 0);
    repack_vt_kernel<<<384, 256, 0, stream>>>(qkvb, (long)256 * 2304, 2304, 128, 192, VtS, 256);
    flash_kernel<<<384, 256, 0, stream>>>(qkvb, (long)256 * 2304, 2304, 192,
                                          qkvb + 64, (long)256 * 2304, 2304, 192,
                                          VtS, attn, 256, scale2);
    gemm_kernel<<<dim3(16, 6), 256, 0, stream>>>(attn, Wlproj, proj_b + l * 768,
                                                 latents, latents, nullptr, 2048, 768, 768, 0);
    ln_kernel<<<2048, 256, 0, stream>>>(latents, ln2_s + l * 768, ln2_b + l * 768, hbuf);
    gemm_kernel<<<dim3(16, 24), 256, 0, stream>>>(hbuf, Wlfc, fc_b + l * 3072,
                                                  nullptr, nullptr, fc1, 2048, 3072, 768, 1);
    gemm_kernel<<<dim3(16, 6), 256, 0, stream>>>(fc1, Wlfc2, fc2_b + l * 768,
                                                 latents, latents, nullptr, 2048, 768, 3072, 0);
  }

  // --- second output: pc passthrough ---
  copy4_kernel<<<96, 256, 0, stream>>>(pc, (float*)d_out + (size_t)2048 * 768, 98304 / 4);
}

// Round 3
// 1572.896 us; speedup vs baseline: 1.4589x; 1.4589x over previous
//
#include <hip/hip_runtime.h>
#include <stdint.h>

typedef unsigned short u16;
typedef __bf16 bf16x8 __attribute__((ext_vector_type(8)));
typedef float f32x4 __attribute__((ext_vector_type(4)));

#define DEVINL __device__ __forceinline__

DEVINL u16 f2bf(float f) {
  union { float f; unsigned u; } c; c.f = f;
  unsigned u = c.u + 0x7FFFu + ((c.u >> 16) & 1u);
  return (u16)(u >> 16);
}

DEVINL float bf2f(u16 v) {
  union { unsigned u; float f; } c; c.u = (unsigned)v << 16;
  return c.f;
}

DEVINL void gl2lds16(const void* g, void* l) {
  __builtin_amdgcn_global_load_lds(
      (const __attribute__((address_space(1))) unsigned int*)g,
      (__attribute__((address_space(3))) unsigned int*)l, 16, 0, 0);
}

// ---------------- fused 4-segment fp32 -> bf16 conversion ----------------
__global__ __launch_bounds__(256) void cvt4_kernel(
    const float* __restrict__ s0, u16* __restrict__ d0, int n0,
    const float* __restrict__ s1, u16* __restrict__ d1, int n1,
    const float* __restrict__ s2, u16* __restrict__ d2, int n2,
    const float* __restrict__ s3, u16* __restrict__ d3, int n3) {
  int i = blockIdx.x * 256 + threadIdx.x;
  const float* s; u16* d;
  if (i < n0) { s = s0; d = d0; }
  else {
    i -= n0;
    if (i < n1) { s = s1; d = d1; }
    else {
      i -= n1;
      if (i < n2) { s = s2; d = d2; }
      else {
        i -= n2;
        if (i >= n3) return;
        s = s3; d = d3;
      }
    }
  }
  float4 v = ((const float4*)s)[i];
  unsigned a = (unsigned)f2bf(v.x) | ((unsigned)f2bf(v.y) << 16);
  unsigned b = (unsigned)f2bf(v.z) | ((unsigned)f2bf(v.w) << 16);
  ((uint2*)d)[i] = make_uint2(a, b);
}

// in_W (768x54) -> bf16 (768x64) zero-padded K
__global__ __launch_bounds__(256) void pad_inw_kernel(const float* __restrict__ src,
                                                      u16* __restrict__ dst) {
  int t = blockIdx.x * 256 + threadIdx.x;  // 768*64
  int r = t >> 6, c = t & 63;
  dst[t] = (c < 54) ? f2bf(src[r * 54 + c]) : (u16)0;
}

// ---------------- fourier embed: (Mc,3)+(Mc,3) -> bf16 (Mc x 64) ----------------
__global__ __launch_bounds__(256) void embed_kernel(const float* __restrict__ pc,
                                                    const float* __restrict__ feats,
                                                    u16* __restrict__ emb) {
  int t = blockIdx.x * 256 + threadIdx.x;
  int p = t >> 6, c = t & 63;
  float v = 0.f;
  if (c < 3) {
    v = pc[p * 3 + c];
  } else if (c < 27) {
    int i = c - 3;
    float f = (float)(1 << (i & 7));
    v = sinf(pc[p * 3 + (i >> 3)] * f);
  } else if (c < 51) {
    int i = c - 27;
    float f = (float)(1 << (i & 7));
    v = cosf(pc[p * 3 + (i >> 3)] * f);
  } else if (c < 54) {
    v = feats[p * 3 + (c - 51)];
  }
  emb[t] = f2bf(v);
}

// ---------------- templated GEMM: C(MxN) = A(MxK,bf16) * Bw(NxK,bf16)^T + bias ----------------
// TM x TN tile, WR x WC wave grid (4 waves total). Verified m97-style staging.
template <int TM, int TN, int WR, int WC>
__global__ __launch_bounds__(256) void gemm_t(
    const u16* __restrict__ A, const u16* __restrict__ Bw,
    const float* __restrict__ bias, const float* __restrict__ resid,
    float* __restrict__ outF, u16* __restrict__ outB,
    int M, int N, int K, int gelu) {
  constexpr int IM = TM / WR / 16;
  constexpr int IN = TN / WC / 16;
  __shared__ u16 As[TM * 32];
  __shared__ u16 Bs[TN * 32];
  const int tid = threadIdx.x;
  const int lane = tid & 63, w = tid >> 6;
  const int l15 = lane & 15, quad = lane >> 4;
  const int mblk = blockIdx.x * TM, nblk = blockIdx.y * TN;
  const int wm = (w % WR) * (TM / WR);
  const int wn = (w / WR) * (TN / WC);

  f32x4 acc[IM][IN];
#pragma unroll
  for (int i = 0; i < IM; i++)
#pragma unroll
    for (int j = 0; j < IN; j++) acc[i][j] = f32x4{0.f, 0.f, 0.f, 0.f};

  for (int k0 = 0; k0 < K; k0 += 32) {
#pragma unroll
    for (int s = tid; s < TM * 4; s += 256) {
      int row = s >> 2, c8 = (s & 3) << 3;
      gl2lds16(A + (size_t)(mblk + row) * K + (k0 + c8), &As[s * 8]);
    }
#pragma unroll
    for (int s = tid; s < TN * 4; s += 256) {
      int row = s >> 2, c8 = (s & 3) << 3;
      gl2lds16(Bw + (size_t)(nblk + row) * K + (k0 + c8), &Bs[s * 8]);
    }
    __syncthreads();
    bf16x8 af[IM], bfr[IN];
#pragma unroll
    for (int i = 0; i < IM; i++)
      af[i] = *(const bf16x8*)&As[(wm + i * 16 + l15) * 32 + quad * 8];
#pragma unroll
    for (int j = 0; j < IN; j++)
      bfr[j] = *(const bf16x8*)&Bs[(wn + j * 16 + l15) * 32 + quad * 8];
#pragma unroll
    for (int i = 0; i < IM; i++)
#pragma unroll
      for (int j = 0; j < IN; j++)
        acc[i][j] = __builtin_amdgcn_mfma_f32_16x16x32_bf16(af[i], bfr[j], acc[i][j], 0, 0, 0);
    __syncthreads();
  }

#pragma unroll
  for (int i = 0; i < IM; i++) {
    int row0 = mblk + wm + i * 16 + quad * 4;
#pragma unroll
    for (int j = 0; j < IN; j++) {
      int col = nblk + wn + j * 16 + l15;
      float bv = bias[col];
#pragma unroll
      for (int r = 0; r < 4; r++) {
        float v = acc[i][j][r] + bv;
        if (gelu) v = 0.5f * v * (1.0f + erff(v * 0.70710678118f));
        size_t idx = (size_t)(row0 + r) * N + col;
        if (resid) v += resid[idx];
        if (outF) outF[idx] = v;
        if (outB) outB[idx] = f2bf(v);
      }
    }
  }
}

// ---------------- V^T repack: In rows (s,d per head) -> Vt[(b*12+h)*64 + d][Skv] ----------------
__global__ __launch_bounds__(256) void repack_vt_kernel(
    const u16* __restrict__ In, long bstride, int rs, int voff, int hs,
    u16* __restrict__ Vt, int Skv) {
  __shared__ u16 tile[64 * 65];
  int nst = Skv >> 6;
  int bid = blockIdx.x;
  int st = bid % nst;
  int bh = bid / nst;
  int h = bh % 12, b = bh / 12;
  const u16* src = In + (size_t)b * bstride + (size_t)(st * 64) * rs + voff + h * hs;
  int tid = threadIdx.x;
#pragma unroll
  for (int p = 0; p < 2; p++) {
    int slot = tid + p * 256;  // s = slot>>3 (64 rows), d8 = (slot&7)*8
    int s = slot >> 3, d8 = (slot & 7) << 3;
    uint4 v = *(const uint4*)(src + (size_t)s * rs + d8);
    u16 tmp[8];
    *(uint4*)tmp = v;
#pragma unroll
    for (int j = 0; j < 8; j++) tile[s * 65 + d8 + j] = tmp[j];
  }
  __syncthreads();
  u16* dst = Vt + ((size_t)(b * 12 + h) * 64) * Skv + st * 64;
#pragma unroll
  for (int p = 0; p < 2; p++) {
    int slot = tid + p * 256;  // d = slot>>3, s8 = (slot&7)*8
    int d = slot >> 3, s8 = (slot & 7) << 3;
    u16 tmp[8];
#pragma unroll
    for (int j = 0; j < 8; j++) tmp[j] = tile[(s8 + j) * 65 + d];
    *(uint4*)(dst + (size_t)d * Skv + s8) = *(uint4*)tmp;
  }
}

// ---------------- flash attention (MFMA, online softmax, optional split-KV) ----------------
// LDS swizzle: chunk c of row r holds global chunk (c-r)&7; reader uses (j+l15)&7
// -> b128 fragment reads are 2-way (free) instead of 16-way conflicted.
__global__ __launch_bounds__(256) void flash_kernel(
    const u16* __restrict__ Q, long qb, int qrs, int qhs,
    const u16* __restrict__ Kp, long kb, int krs, int khs,
    const u16* __restrict__ Vt, u16* __restrict__ Out,
    u16* __restrict__ Part, float* __restrict__ Ml,
    int Skv, int nsplit, int kvlen, float scale2) {
  __shared__ u16 Qs[64 * 64];
  __shared__ u16 Ks[64 * 64];
  __shared__ u16 Vs[64 * 64];
  __shared__ u16 Ps[64 * 72];

  const int tid = threadIdx.x;
  const int lane = tid & 63, w = tid >> 6;
  const int l15 = lane & 15, quad = lane >> 4;

  int bid = blockIdx.x;
  int per_bh = nsplit << 2;
  int bh = bid / per_bh;
  int rem = bid - bh * per_bh;
  int split = rem >> 2, qt = rem & 3;
  int h = bh % 12, b = bh / 12;

  const u16* Qbase = Q + (size_t)b * qb + (size_t)(qt * 64) * qrs + h * qhs;
  const u16* Kbase = Kp + (size_t)b * kb + (size_t)h * khs;
  const u16* Vbase = Vt + ((size_t)(b * 12 + h) * 64) * Skv;

#pragma unroll
  for (int p = 0; p < 2; ++p) {
    int slot = tid + p * 256;
    int row = slot >> 3, c = slot & 7;
    int cg = (c - row) & 7;
    gl2lds16(Qbase + (size_t)row * qrs + cg * 8, &Qs[slot * 8]);
  }
  __syncthreads();

  bf16x8 qa[2];
#pragma unroll
  for (int kk = 0; kk < 2; kk++)
    qa[kk] = *(const bf16x8*)&Qs[(w * 16 + l15) * 64 + ((kk * 4 + quad + l15) & 7) * 8];

  f32x4 zero = {0.f, 0.f, 0.f, 0.f};
  f32x4 O[4];
  float m_i[4], l_i[4];
#pragma unroll
  for (int d = 0; d < 4; d++) O[d] = zero;
#pragma unroll
  for (int r = 0; r < 4; r++) { m_i[r] = -1e30f; l_i[r] = 0.f; }

  int kt0 = split * kvlen;
  for (int kt = kt0; kt < kt0 + kvlen; kt += 64) {
#pragma unroll
    for (int p = 0; p < 2; ++p) {
      int slot = tid + p * 256;
      int row = slot >> 3, c = slot & 7;
      int cg = (c - row) & 7;
      gl2lds16(Kbase + (size_t)(kt + row) * krs + cg * 8, &Ks[slot * 8]);
      gl2lds16(Vbase + (size_t)row * Skv + kt + cg * 8, &Vs[slot * 8]);
    }
    __syncthreads();

    f32x4 S[4];
#pragma unroll
    for (int j = 0; j < 4; j++) S[j] = zero;
#pragma unroll
    for (int kk = 0; kk < 2; kk++) {
#pragma unroll
      for (int j = 0; j < 4; j++) {
        bf16x8 kf = *(const bf16x8*)&Ks[(j * 16 + l15) * 64 + ((kk * 4 + quad + l15) & 7) * 8];
        S[j] = __builtin_amdgcn_mfma_f32_16x16x32_bf16(qa[kk], kf, S[j], 0, 0, 0);
      }
    }
    float alpha[4];
#pragma unroll
    for (int r = 0; r < 4; r++) {
      float s0 = S[0][r] * scale2, s1 = S[1][r] * scale2;
      float s2 = S[2][r] * scale2, s3 = S[3][r] * scale2;
      S[0][r] = s0; S[1][r] = s1; S[2][r] = s2; S[3][r] = s3;
      float mx = fmaxf(fmaxf(s0, s1), fmaxf(s2, s3));
#pragma unroll
      for (int msk = 1; msk < 16; msk <<= 1) mx = fmaxf(mx, __shfl_xor(mx, msk, 64));
      float mnew = fmaxf(m_i[r], mx);
      float al = __expf(m_i[r] - mnew);
      m_i[r] = mnew;
      alpha[r] = al;
      float sum = 0.f;
#pragma unroll
      for (int j = 0; j < 4; j++) {
        float pv = __expf(S[j][r] - mnew);
        S[j][r] = pv;
        sum += pv;
      }
#pragma unroll
      for (int msk = 1; msk < 16; msk <<= 1) sum += __shfl_xor(sum, msk, 64);
      l_i[r] = l_i[r] * al + sum;
    }
    // P -> LDS (wave-private rows), C-layout -> A-layout transform
#pragma unroll
    for (int j = 0; j < 4; j++)
#pragma unroll
      for (int r = 0; r < 4; r++)
        Ps[(w * 16 + quad * 4 + r) * 72 + j * 16 + l15] = f2bf(S[j][r]);
#pragma unroll
    for (int d = 0; d < 4; d++)
#pragma unroll
      for (int r = 0; r < 4; r++) O[d][r] *= alpha[r];
    __asm__ __volatile__("s_waitcnt lgkmcnt(0)" ::: "memory");
#pragma unroll
    for (int kk = 0; kk < 2; kk++) {
      bf16x8 pa = *(const bf16x8*)&Ps[(w * 16 + l15) * 72 + kk * 32 + quad * 8];
#pragma unroll
      for (int d = 0; d < 4; d++) {
        bf16x8 vf = *(const bf16x8*)&Vs[(d * 16 + l15) * 64 + ((kk * 4 + quad + l15) & 7) * 8];
        O[d] = __builtin_amdgcn_mfma_f32_16x16x32_bf16(pa, vf, O[d], 0, 0, 0);
      }
    }
    __syncthreads();
  }

  if (nsplit == 1) {
    u16* Ob = Out + ((size_t)(b * 256 + qt * 64 + w * 16 + quad * 4)) * 768 + h * 64 + l15;
#pragma unroll
    for (int d = 0; d < 4; d++)
#pragma unroll
      for (int r = 0; r < 4; r++) {
        float v = O[d][r] / l_i[r];
        Ob[(size_t)r * 768 + d * 16] = f2bf(v);
      }
  } else {
    // partial: raw numerator O (bf16) + per-row m,l
    u16* Pb = Part + ((size_t)(bh * 4 + qt) * nsplit + split) * 4096;
    int rowb = w * 16 + quad * 4;
#pragma unroll
    for (int d = 0; d < 4; d++)
#pragma unroll
      for (int r = 0; r < 4; r++)
        Pb[(rowb + r) * 64 + d * 16 + l15] = f2bf(O[d][r]);
    if (l15 == 0) {
      float* MlB = Ml + ((size_t)(bh * 4 + qt) * nsplit + split) * 128;
#pragma unroll
      for (int r = 0; r < 4; r++) {
        MlB[rowb + r] = m_i[r];
        MlB[64 + rowb + r] = l_i[r];
      }
    }
  }
}

// ---------------- split-KV reduce: combine nsplit partials -> attn bf16 ----------------
__global__ __launch_bounds__(256) void freduce_kernel(
    const u16* __restrict__ Part, const float* __restrict__ Ml,
    u16* __restrict__ Out, int nsplit) {
  int bid = blockIdx.x;
  int qt = bid & 3, bh = bid >> 2;
  int h = bh % 12, b = bh / 12;
  int tid = threadIdx.x;
  int r = tid >> 2, dc = tid & 3;
  const float* mlb = Ml + (size_t)(bh * 4 + qt) * nsplit * 128;
  float M = -1e30f;
  for (int s = 0; s < nsplit; s++) M = fmaxf(M, mlb[s * 128 + r]);
  float L = 0.f;
  float accv[16];
#pragma unroll
  for (int i = 0; i < 16; i++) accv[i] = 0.f;
  const u16* pb = Part + (size_t)(bh * 4 + qt) * nsplit * 4096 + r * 64 + dc * 16;
  for (int s = 0; s < nsplit; s++) {
    float wgt = __expf(mlb[s * 128 + r] - M);
    L += wgt * mlb[s * 128 + 64 + r];
#pragma unroll
    for (int i = 0; i < 16; i++) accv[i] += wgt * bf2f(pb[s * 4096 + i]);
  }
  float inv = 1.f / L;
  u16* ob = Out + ((size_t)(b * 256 + qt * 64 + r)) * 768 + h * 64 + dc * 16;
#pragma unroll
  for (int i = 0; i < 16; i++) ob[i] = f2bf(accv[i] * inv);
}

// ---------------- LayerNorm: fp32 (2048x768) -> bf16 with scale/bias ----------------
__global__ __launch_bounds__(256) void ln_kernel(const float* __restrict__ X,
                                                 const float* __restrict__ sc,
                                                 const float* __restrict__ bi,
                                                 u16* __restrict__ Hout) {
  int row = blockIdx.x;
  int tid = threadIdx.x;
  const float* x = X + (size_t)row * 768;
  float v0 = x[tid], v1 = x[tid + 256], v2 = x[tid + 512];
  float s = v0 + v1 + v2;
  float q = v0 * v0 + v1 * v1 + v2 * v2;
#pragma unroll
  for (int m = 1; m < 64; m <<= 1) {
    s += __shfl_xor(s, m, 64);
    q += __shfl_xor(q, m, 64);
  }
  __shared__ float rs[4], rq[4];
  if ((tid & 63) == 0) { rs[tid >> 6] = s; rq[tid >> 6] = q; }
  __syncthreads();
  s = rs[0] + rs[1] + rs[2] + rs[3];
  q = rq[0] + rq[1] + rq[2] + rq[3];
  float mu = s * (1.f / 768.f);
  float var = q * (1.f / 768.f) - mu * mu;
  float rstd = rsqrtf(var + 1e-5f);
  u16* ho = Hout + (size_t)row * 768;
  ho[tid]       = f2bf((v0 - mu) * rstd * sc[tid]       + bi[tid]);
  ho[tid + 256] = f2bf((v1 - mu) * rstd * sc[tid + 256] + bi[tid + 256]);
  ho[tid + 512] = f2bf((v2 - mu) * rstd * sc[tid + 512] + bi[tid + 512]);
}

__global__ __launch_bounds__(256) void copy4_kernel(const float* __restrict__ src,
                                                    float* __restrict__ dst, int n4) {
  int i = blockIdx.x * 256 + threadIdx.x;
  if (i < n4) ((float4*)dst)[i] = ((const float4*)src)[i];
}

// =====================================================================
extern "C" void kernel_launch(void* const* d_in, const int* in_sizes, int n_in,
                              void* d_out, int out_size, void* d_ws, size_t ws_size,
                              hipStream_t stream) {
  const float* pc        = (const float*)d_in[0];
  const float* feats     = (const float*)d_in[1];
  const float* query     = (const float*)d_in[2];
  const float* in_W      = (const float*)d_in[3];
  const float* in_b      = (const float*)d_in[4];
  const float* ca_qkv_W  = (const float*)d_in[5];
  const float* ca_qkv_b  = (const float*)d_in[6];
  const float* ca_proj_W = (const float*)d_in[7];
  const float* ca_proj_b = (const float*)d_in[8];
  const float* ln1_s     = (const float*)d_in[9];
  const float* ln1_b     = (const float*)d_in[10];
  const float* qkv_W     = (const float*)d_in[11];
  const float* qkv_b     = (const float*)d_in[12];
  const float* proj_W    = (const float*)d_in[13];
  const float* proj_b    = (const float*)d_in[14];
  const float* ln2_s     = (const float*)d_in[15];
  const float* ln2_b     = (const float*)d_in[16];
  const float* fc_W      = (const float*)d_in[17];
  const float* fc_b      = (const float*)d_in[18];
  const float* fc2_W     = (const float*)d_in[19];
  const float* fc2_b     = (const float*)d_in[20];

  char* base = (char*)d_ws;
  size_t off = 0;
  auto alloc = [&](size_t bytes) -> char* {
    char* p = base + off;
    off += (bytes + 255) & ~(size_t)255;
    return p;
  };

  // ---- fixed region (~41 MB) ----
  u16* Wq      = (u16*)alloc(768 * 64 * 2);
  u16* Wquery  = (u16*)alloc(256 * 768 * 2);
  u16* Wcaqkv  = (u16*)alloc(2304 * 768 * 2);
  u16* Wcaproj = (u16*)alloc(768 * 768 * 2);
  u16* Wlqkv   = (u16*)alloc(2304 * 768 * 2);   // per-layer rotating
  u16* Wlproj  = (u16*)alloc(768 * 768 * 2);
  u16* Wlfc    = (u16*)alloc(3072 * 768 * 2);
  u16* Wlfc2   = (u16*)alloc(768 * 3072 * 2);
  u16* qc      = (u16*)alloc(256 * 768 * 2);
  u16* attn    = (u16*)alloc((size_t)2048 * 768 * 2);
  u16* hbuf    = (u16*)alloc((size_t)2048 * 768 * 2);
  // union region, 13.37 MB:
  //   layers:  qkvb 9.44MB + VtS 3.15MB  |  fc1 12.58MB
  //   cross:   flash partials 12.58MB + Ml 0.79MB
  char* uni    = alloc(13369344);
  u16* qkvb    = (u16*)uni;
  u16* VtS     = (u16*)(uni + 9437184);
  u16* fc1     = (u16*)uni;
  u16* Part    = (u16*)uni;
  float* Ml    = (float*)(uni + 12582912);

  // ---- adaptive cross-attn chunking by ws budget ----
  size_t fixed_end = off;
  size_t per_b = (size_t)4096 * 64 * 2 + (size_t)4096 * 768 * 2 + (size_t)4096 * 1536 * 2;
  int CB;
  if (fixed_end + 8 * per_b + 4096 <= ws_size) CB = 8;
  else if (fixed_end + 2 * per_b + 4096 <= ws_size) CB = 2;
  else CB = 1;

  u16* emb   = (u16*)alloc((size_t)CB * 4096 * 64 * 2);
  u16* dataB = (u16*)alloc((size_t)CB * 4096 * 768 * 2);
  u16* kvb   = (u16*)alloc((size_t)CB * 4096 * 1536 * 2);
  u16* VtC   = dataB;  // alias: data dead before repack writes VtC

  float* latents = (float*)d_out;  // (2048 x 768) fp32
  const float scale2 = 0.125f;     // SCALE^2 = 1/sqrt(D_HEAD)

  // --- upfront conversions (cross-attn weights, one fused launch) ---
  {
    int n0 = 256 * 768 / 4, n1 = 2304 * 768 / 4, n2 = 768 * 768 / 4;
    cvt4_kernel<<<(n0 + n1 + n2 + 255) / 256, 256, 0, stream>>>(
        query, Wquery, n0, ca_qkv_W, Wcaqkv, n1, ca_proj_W, Wcaproj, n2,
        nullptr, nullptr, 0);
  }
  pad_inw_kernel<<<192, 256, 0, stream>>>(in_W, Wq);

  // --- latent q projection (batch-independent) ---
  gemm_t<64, 64, 2, 2><<<dim3(4, 12), 256, 0, stream>>>(
      Wquery, Wcaqkv, ca_qkv_b, nullptr, nullptr, qc, 256, 768, 768, 0);

  // --- cross-attention, chunked over batches ---
  int nchunk = 8 / CB;
  for (int c = 0; c < nchunk; ++c) {
    int Mc = CB * 4096;
    const float* pc_c = pc + (size_t)c * Mc * 3;
    const float* ft_c = feats + (size_t)c * Mc * 3;
    embed_kernel<<<Mc / 4, 256, 0, stream>>>(pc_c, ft_c, emb);
    gemm_t<128, 128, 2, 2><<<dim3(Mc / 128, 6), 256, 0, stream>>>(
        emb, Wq, in_b, nullptr, nullptr, dataB, Mc, 768, 64, 0);
    gemm_t<128, 128, 2, 2><<<dim3(Mc / 128, 12), 256, 0, stream>>>(
        dataB, Wcaqkv + (size_t)768 * 768, ca_qkv_b + 768, nullptr, nullptr, kvb,
        Mc, 1536, 768, 0);
    repack_vt_kernel<<<CB * 12 * 64, 256, 0, stream>>>(
        kvb, (long)4096 * 1536, 1536, 768, 64, VtC, 4096);
    // split-KV flash: nsplit=4, 1024 kv per split
    flash_kernel<<<CB * 12 * 16, 256, 0, stream>>>(
        qc, 0L, 768, 64, kvb, (long)4096 * 1536, 1536, 64, VtC,
        nullptr, Part, Ml, 4096, 4, 1024, scale2);
    freduce_kernel<<<CB * 48, 256, 0, stream>>>(
        Part, Ml, attn + (size_t)c * CB * 256 * 768, 4);
  }
  gemm_t<64, 64, 2, 2><<<dim3(32, 12), 256, 0, stream>>>(
      attn, Wcaproj, ca_proj_b, nullptr, latents, nullptr, 2048, 768, 768, 0);

  // --- transformer layers ---
  for (int l = 0; l < 8; ++l) {
    {
      int n0 = 2304 * 768 / 4, n1 = 768 * 768 / 4, n2 = 3072 * 768 / 4, n3 = n2;
      cvt4_kernel<<<(n0 + n1 + n2 + n3 + 255) / 256, 256, 0, stream>>>(
          qkv_W + (size_t)l * 2304 * 768, Wlqkv, n0,
          proj_W + (size_t)l * 768 * 768, Wlproj, n1,
          fc_W + (size_t)l * 3072 * 768, Wlfc, n2,
          fc2_W + (size_t)l * 768 * 3072, Wlfc2, n3);
    }
    ln_kernel<<<2048, 256, 0, stream>>>(latents, ln1_s + l * 768, ln1_b + l * 768, hbuf);
    gemm_t<64, 128, 1, 4><<<dim3(32, 18), 256, 0, stream>>>(
        hbuf, Wlqkv, qkv_b + l * 2304, nullptr, nullptr, qkvb, 2048, 2304, 768, 0);
    repack_vt_kernel<<<384, 256, 0, stream>>>(qkvb, (long)256 * 2304, 2304, 128, 192, VtS, 256);
    flash_kernel<<<384, 256, 0, stream>>>(
        qkvb, (long)256 * 2304, 2304, 192, qkvb + 64, (long)256 * 2304, 2304, 192,
        VtS, attn, nullptr, nullptr, 256, 1, 256, scale2);
    gemm_t<64, 64, 2, 2><<<dim3(32, 12), 256, 0, stream>>>(
        attn, Wlproj, proj_b + l * 768, latents, latents, nullptr, 2048, 768, 768, 0);
    ln_kernel<<<2048, 256, 0, stream>>>(latents, ln2_s + l * 768, ln2_b + l * 768, hbuf);
    gemm_t<64, 128, 1, 4><<<dim3(32, 24), 256, 0, stream>>>(
        hbuf, Wlfc, fc_b + l * 3072, nullptr, nullptr, fc1, 2048, 3072, 768, 1);
    gemm_t<64, 64, 2, 2><<<dim3(32, 12), 256, 0, stream>>>(
        fc1, Wlfc2, fc2_b + l * 768, latents, latents, nullptr, 2048, 768, 3072, 0);
  }

  // --- second output: pc passthrough ---
  copy4_kernel<<<96, 256, 0, stream>>>(pc, (float*)d_out + (size_t)2048 * 768, 98304 / 4);
}

// Round 4
// 1494.709 us; speedup vs baseline: 1.5352x; 1.0523x over previous
//
#include <hip/hip_runtime.h>
#include <stdint.h>

typedef unsigned short u16;
typedef __bf16 bf16x8 __attribute__((ext_vector_type(8)));
typedef float f32x4 __attribute__((ext_vector_type(4)));

#define DEVINL __device__ __forceinline__

DEVINL u16 f2bf(float f) {
  union { float f; unsigned u; } c; c.f = f;
  unsigned u = c.u + 0x7FFFu + ((c.u >> 16) & 1u);
  return (u16)(u >> 16);
}

DEVINL float bf2f(u16 v) {
  union { unsigned u; float f; } c; c.u = (unsigned)v << 16;
  return c.f;
}

DEVINL void gl2lds16(const void* g, void* l) {
  __builtin_amdgcn_global_load_lds(
      (const __attribute__((address_space(1))) unsigned int*)g,
      (__attribute__((address_space(3))) unsigned int*)l, 16, 0, 0);
}

// ---------------- fused 4-segment fp32 -> bf16 conversion ----------------
__global__ __launch_bounds__(256) void cvt4_kernel(
    const float* __restrict__ s0, u16* __restrict__ d0, int n0,
    const float* __restrict__ s1, u16* __restrict__ d1, int n1,
    const float* __restrict__ s2, u16* __restrict__ d2, int n2,
    const float* __restrict__ s3, u16* __restrict__ d3, int n3) {
  int i = blockIdx.x * 256 + threadIdx.x;
  const float* s; u16* d;
  if (i < n0) { s = s0; d = d0; }
  else {
    i -= n0;
    if (i < n1) { s = s1; d = d1; }
    else {
      i -= n1;
      if (i < n2) { s = s2; d = d2; }
      else {
        i -= n2;
        if (i >= n3) return;
        s = s3; d = d3;
      }
    }
  }
  float4 v = ((const float4*)s)[i];
  unsigned a = (unsigned)f2bf(v.x) | ((unsigned)f2bf(v.y) << 16);
  unsigned b = (unsigned)f2bf(v.z) | ((unsigned)f2bf(v.w) << 16);
  ((uint2*)d)[i] = make_uint2(a, b);
}

// in_W (768x54) -> bf16 (768x64) zero-padded K
__global__ __launch_bounds__(256) void pad_inw_kernel(const float* __restrict__ src,
                                                      u16* __restrict__ dst) {
  int t = blockIdx.x * 256 + threadIdx.x;  // 768*64
  int r = t >> 6, c = t & 63;
  dst[t] = (c < 54) ? f2bf(src[r * 54 + c]) : (u16)0;
}

// ---------------- fourier embed ----------------
__global__ __launch_bounds__(256) void embed_kernel(const float* __restrict__ pc,
                                                    const float* __restrict__ feats,
                                                    u16* __restrict__ emb) {
  int t = blockIdx.x * 256 + threadIdx.x;
  int p = t >> 6, c = t & 63;
  float v = 0.f;
  if (c < 3) {
    v = pc[p * 3 + c];
  } else if (c < 27) {
    int i = c - 3;
    float f = (float)(1 << (i & 7));
    v = sinf(pc[p * 3 + (i >> 3)] * f);
  } else if (c < 51) {
    int i = c - 27;
    float f = (float)(1 << (i & 7));
    v = cosf(pc[p * 3 + (i >> 3)] * f);
  } else if (c < 54) {
    v = feats[p * 3 + (c - 51)];
  }
  emb[t] = f2bf(v);
}

// ---------------- templated GEMM ----------------
// MODE 0: all tiles "normal": operand-swapped MFMA -> lane=row(m), regs=4 consecutive cols(n)
//         -> float4 bias/resid/outF, dwordx2 bf16 stores.
// MODE 1: blocks y<vy normal; y>=vy write V transposed into vt[b*768+nv][s] (original
//         operand order: regs = 4 consecutive rows m = consecutive s).
template <int TM, int TN, int WR, int WC, int MODE>
__global__ __launch_bounds__(256) void gemm_t(
    const u16* __restrict__ A, const u16* __restrict__ Bw,
    const float* __restrict__ bias, const float* __restrict__ resid,
    float* __restrict__ outF, u16* __restrict__ outB,
    int M, int N, int Nout, int K, int gelu,
    u16* __restrict__ vt, int vy, int skvt, int bsh) {
  constexpr int IM = TM / WR / 16;
  constexpr int IN = TN / WC / 16;
  __shared__ u16 As[TM * 32];
  __shared__ u16 Bs[TN * 32];
  const int tid = threadIdx.x;
  const int lane = tid & 63, w = tid >> 6;
  const int l15 = lane & 15, quad = lane >> 4;
  const int mblk = blockIdx.x * TM, nblk = blockIdx.y * TN;
  const int wm = (w % WR) * (TM / WR);
  const int wn = (w / WR) * (TN / WC);

  f32x4 acc[IM][IN];
#pragma unroll
  for (int i = 0; i < IM; i++)
#pragma unroll
    for (int j = 0; j < IN; j++) acc[i][j] = f32x4{0.f, 0.f, 0.f, 0.f};

  const bool tv = (MODE == 1) && ((int)blockIdx.y >= vy);

  if (!tv) {
    for (int k0 = 0; k0 < K; k0 += 32) {
#pragma unroll
      for (int s = tid; s < TM * 4; s += 256) {
        int row = s >> 2, c8 = (s & 3) << 3;
        gl2lds16(A + (size_t)(mblk + row) * K + (k0 + c8), &As[s * 8]);
      }
#pragma unroll
      for (int s = tid; s < TN * 4; s += 256) {
        int row = s >> 2, c8 = (s & 3) << 3;
        gl2lds16(Bw + (size_t)(nblk + row) * K + (k0 + c8), &Bs[s * 8]);
      }
      __syncthreads();
      bf16x8 af[IM], bfr[IN];
#pragma unroll
      for (int i = 0; i < IM; i++)
        af[i] = *(const bf16x8*)&As[(wm + i * 16 + l15) * 32 + quad * 8];
#pragma unroll
      for (int j = 0; j < IN; j++)
        bfr[j] = *(const bf16x8*)&Bs[(wn + j * 16 + l15) * 32 + quad * 8];
#pragma unroll
      for (int i = 0; i < IM; i++)
#pragma unroll
        for (int j = 0; j < IN; j++)
          acc[i][j] = __builtin_amdgcn_mfma_f32_16x16x32_bf16(bfr[j], af[i], acc[i][j], 0, 0, 0);
      __syncthreads();
    }
    // normal epilogue: lane l15 -> m, regs -> 4 consecutive n
#pragma unroll
    for (int i = 0; i < IM; i++) {
      int m = mblk + wm + i * 16 + l15;
#pragma unroll
      for (int j = 0; j < IN; j++) {
        int n0 = nblk + wn + j * 16 + quad * 4;
        float4 bv = *(const float4*)&bias[n0];
        float v0 = acc[i][j][0] + bv.x;
        float v1 = acc[i][j][1] + bv.y;
        float v2 = acc[i][j][2] + bv.z;
        float v3 = acc[i][j][3] + bv.w;
        if (gelu) {
          v0 = 0.5f * v0 * (1.0f + erff(v0 * 0.70710678118f));
          v1 = 0.5f * v1 * (1.0f + erff(v1 * 0.70710678118f));
          v2 = 0.5f * v2 * (1.0f + erff(v2 * 0.70710678118f));
          v3 = 0.5f * v3 * (1.0f + erff(v3 * 0.70710678118f));
        }
        size_t idx = (size_t)m * Nout + n0;
        if (resid) {
          float4 rv = *(const float4*)&resid[idx];
          v0 += rv.x; v1 += rv.y; v2 += rv.z; v3 += rv.w;
        }
        if (outF) {
          float4 ov = {v0, v1, v2, v3};
          *(float4*)&outF[idx] = ov;
        }
        if (outB) {
          unsigned lo = (unsigned)f2bf(v0) | ((unsigned)f2bf(v1) << 16);
          unsigned hi = (unsigned)f2bf(v2) | ((unsigned)f2bf(v3) << 16);
          *(uint2*)&outB[idx] = make_uint2(lo, hi);
        }
      }
    }
  } else {
    for (int k0 = 0; k0 < K; k0 += 32) {
#pragma unroll
      for (int s = tid; s < TM * 4; s += 256) {
        int row = s >> 2, c8 = (s & 3) << 3;
        gl2lds16(A + (size_t)(mblk + row) * K + (k0 + c8), &As[s * 8]);
      }
#pragma unroll
      for (int s = tid; s < TN * 4; s += 256) {
        int row = s >> 2, c8 = (s & 3) << 3;
        gl2lds16(Bw + (size_t)(nblk + row) * K + (k0 + c8), &Bs[s * 8]);
      }
      __syncthreads();
      bf16x8 af[IM], bfr[IN];
#pragma unroll
      for (int i = 0; i < IM; i++)
        af[i] = *(const bf16x8*)&As[(wm + i * 16 + l15) * 32 + quad * 8];
#pragma unroll
      for (int j = 0; j < IN; j++)
        bfr[j] = *(const bf16x8*)&Bs[(wn + j * 16 + l15) * 32 + quad * 8];
#pragma unroll
      for (int i = 0; i < IM; i++)
#pragma unroll
        for (int j = 0; j < IN; j++)
          acc[i][j] = __builtin_amdgcn_mfma_f32_16x16x32_bf16(af[i], bfr[j], acc[i][j], 0, 0, 0);
      __syncthreads();
    }
    // transposed-V epilogue: lane l15 -> n, regs -> 4 consecutive m (= consecutive s)
    int msk = (1 << bsh) - 1;
#pragma unroll
    for (int j = 0; j < IN; j++) {
      int n = nblk + wn + j * 16 + l15;
      float bv = bias[n];
      int nv = n - vy * TN;  // local V col = h*64+d
#pragma unroll
      for (int i = 0; i < IM; i++) {
        int m0 = mblk + wm + i * 16 + quad * 4;
        int b = m0 >> bsh;
        int s0 = m0 & msk;
        float v0 = acc[i][j][0] + bv;
        float v1 = acc[i][j][1] + bv;
        float v2 = acc[i][j][2] + bv;
        float v3 = acc[i][j][3] + bv;
        unsigned lo = (unsigned)f2bf(v0) | ((unsigned)f2bf(v1) << 16);
        unsigned hi = (unsigned)f2bf(v2) | ((unsigned)f2bf(v3) << 16);
        size_t addr = (size_t)(b * 768 + nv) * skvt + s0;
        *(uint2*)&vt[addr] = make_uint2(lo, hi);
      }
    }
  }
}

// ---------------- V^T repack (layer self-attn only) ----------------
__global__ __launch_bounds__(256) void repack_vt_kernel(
    const u16* __restrict__ In, long bstride, int rs, int voff, int hs,
    u16* __restrict__ Vt, int Skv) {
  __shared__ u16 tile[64 * 65];
  int nst = Skv >> 6;
  int bid = blockIdx.x;
  int st = bid % nst;
  int bh = bid / nst;
  int h = bh % 12, b = bh / 12;
  const u16* src = In + (size_t)b * bstride + (size_t)(st * 64) * rs + voff + h * hs;
  int tid = threadIdx.x;
#pragma unroll
  for (int p = 0; p < 2; p++) {
    int slot = tid + p * 256;
    int s = slot >> 3, d8 = (slot & 7) << 3;
    uint4 v = *(const uint4*)(src + (size_t)s * rs + d8);
    u16 tmp[8];
    *(uint4*)tmp = v;
#pragma unroll
    for (int j = 0; j < 8; j++) tile[s * 65 + d8 + j] = tmp[j];
  }
  __syncthreads();
  u16* dst = Vt + ((size_t)(b * 12 + h) * 64) * Skv + st * 64;
#pragma unroll
  for (int p = 0; p < 2; p++) {
    int slot = tid + p * 256;
    int d = slot >> 3, s8 = (slot & 7) << 3;
    u16 tmp[8];
#pragma unroll
    for (int j = 0; j < 8; j++) tmp[j] = tile[(s8 + j) * 65 + d];
    *(uint4*)(dst + (size_t)d * Skv + s8) = *(uint4*)tmp;
  }
}

// ---------------- flash attention (MFMA, online softmax, optional split-KV) ----------------
__global__ __launch_bounds__(256) void flash_kernel(
    const u16* __restrict__ Q, long qb, int qrs, int qhs,
    const u16* __restrict__ Kp, long kb, int krs, int khs,
    const u16* __restrict__ Vt, u16* __restrict__ Out,
    u16* __restrict__ Part, float* __restrict__ Ml,
    int Skv, int nsplit, int kvlen, float scale2) {
  __shared__ u16 Qs[64 * 64];
  __shared__ u16 Ks[64 * 64];
  __shared__ u16 Vs[64 * 64];
  __shared__ u16 Ps[64 * 72];

  const int tid = threadIdx.x;
  const int lane = tid & 63, w = tid >> 6;
  const int l15 = lane & 15, quad = lane >> 4;

  int bid = blockIdx.x;
  int per_bh = nsplit << 2;
  int bh = bid / per_bh;
  int rem = bid - bh * per_bh;
  int split = rem >> 2, qt = rem & 3;
  int h = bh % 12, b = bh / 12;

  const u16* Qbase = Q + (size_t)b * qb + (size_t)(qt * 64) * qrs + h * qhs;
  const u16* Kbase = Kp + (size_t)b * kb + (size_t)h * khs;
  const u16* Vbase = Vt + ((size_t)(b * 12 + h) * 64) * Skv;

#pragma unroll
  for (int p = 0; p < 2; ++p) {
    int slot = tid + p * 256;
    int row = slot >> 3, c = slot & 7;
    int cg = (c - row) & 7;
    gl2lds16(Qbase + (size_t)row * qrs + cg * 8, &Qs[slot * 8]);
  }
  __syncthreads();

  bf16x8 qa[2];
#pragma unroll
  for (int kk = 0; kk < 2; kk++)
    qa[kk] = *(const bf16x8*)&Qs[(w * 16 + l15) * 64 + ((kk * 4 + quad + l15) & 7) * 8];

  f32x4 zero = {0.f, 0.f, 0.f, 0.f};
  f32x4 O[4];
  float m_i[4], l_i[4];
#pragma unroll
  for (int d = 0; d < 4; d++) O[d] = zero;
#pragma unroll
  for (int r = 0; r < 4; r++) { m_i[r] = -1e30f; l_i[r] = 0.f; }

  int kt0 = split * kvlen;
  for (int kt = kt0; kt < kt0 + kvlen; kt += 64) {
#pragma unroll
    for (int p = 0; p < 2; ++p) {
      int slot = tid + p * 256;
      int row = slot >> 3, c = slot & 7;
      int cg = (c - row) & 7;
      gl2lds16(Kbase + (size_t)(kt + row) * krs + cg * 8, &Ks[slot * 8]);
      gl2lds16(Vbase + (size_t)row * Skv + kt + cg * 8, &Vs[slot * 8]);
    }
    __syncthreads();

    f32x4 S[4];
#pragma unroll
    for (int j = 0; j < 4; j++) S[j] = zero;
#pragma unroll
    for (int kk = 0; kk < 2; kk++) {
#pragma unroll
      for (int j = 0; j < 4; j++) {
        bf16x8 kf = *(const bf16x8*)&Ks[(j * 16 + l15) * 64 + ((kk * 4 + quad + l15) & 7) * 8];
        S[j] = __builtin_amdgcn_mfma_f32_16x16x32_bf16(qa[kk], kf, S[j], 0, 0, 0);
      }
    }
    float alpha[4];
#pragma unroll
    for (int r = 0; r < 4; r++) {
      float s0 = S[0][r] * scale2, s1 = S[1][r] * scale2;
      float s2 = S[2][r] * scale2, s3 = S[3][r] * scale2;
      S[0][r] = s0; S[1][r] = s1; S[2][r] = s2; S[3][r] = s3;
      float mx = fmaxf(fmaxf(s0, s1), fmaxf(s2, s3));
#pragma unroll
      for (int msk = 1; msk < 16; msk <<= 1) mx = fmaxf(mx, __shfl_xor(mx, msk, 64));
      float mnew = fmaxf(m_i[r], mx);
      float al = __expf(m_i[r] - mnew);
      m_i[r] = mnew;
      alpha[r] = al;
      float sum = 0.f;
#pragma unroll
      for (int j = 0; j < 4; j++) {
        float pv = __expf(S[j][r] - mnew);
        S[j][r] = pv;
        sum += pv;
      }
#pragma unroll
      for (int msk = 1; msk < 16; msk <<= 1) sum += __shfl_xor(sum, msk, 64);
      l_i[r] = l_i[r] * al + sum;
    }
#pragma unroll
    for (int j = 0; j < 4; j++)
#pragma unroll
      for (int r = 0; r < 4; r++)
        Ps[(w * 16 + quad * 4 + r) * 72 + j * 16 + l15] = f2bf(S[j][r]);
#pragma unroll
    for (int d = 0; d < 4; d++)
#pragma unroll
      for (int r = 0; r < 4; r++) O[d][r] *= alpha[r];
    __asm__ __volatile__("s_waitcnt lgkmcnt(0)" ::: "memory");
#pragma unroll
    for (int kk = 0; kk < 2; kk++) {
      bf16x8 pa = *(const bf16x8*)&Ps[(w * 16 + l15) * 72 + kk * 32 + quad * 8];
#pragma unroll
      for (int d = 0; d < 4; d++) {
        bf16x8 vf = *(const bf16x8*)&Vs[(d * 16 + l15) * 64 + ((kk * 4 + quad + l15) & 7) * 8];
        O[d] = __builtin_amdgcn_mfma_f32_16x16x32_bf16(pa, vf, O[d], 0, 0, 0);
      }
    }
    __syncthreads();
  }

  if (nsplit == 1) {
    u16* Ob = Out + ((size_t)(b * 256 + qt * 64 + w * 16 + quad * 4)) * 768 + h * 64 + l15;
#pragma unroll
    for (int d = 0; d < 4; d++)
#pragma unroll
      for (int r = 0; r < 4; r++) {
        float v = O[d][r] / l_i[r];
        Ob[(size_t)r * 768 + d * 16] = f2bf(v);
      }
  } else {
    u16* Pb = Part + ((size_t)(bh * 4 + qt) * nsplit + split) * 4096;
    int rowb = w * 16 + quad * 4;
#pragma unroll
    for (int d = 0; d < 4; d++)
#pragma unroll
      for (int r = 0; r < 4; r++)
        Pb[(rowb + r) * 64 + d * 16 + l15] = f2bf(O[d][r]);
    if (l15 == 0) {
      float* MlB = Ml + ((size_t)(bh * 4 + qt) * nsplit + split) * 128;
#pragma unroll
      for (int r = 0; r < 4; r++) {
        MlB[rowb + r] = m_i[r];
        MlB[64 + rowb + r] = l_i[r];
      }
    }
  }
}

// ---------------- split-KV reduce ----------------
__global__ __launch_bounds__(256) void freduce_kernel(
    const u16* __restrict__ Part, const float* __restrict__ Ml,
    u16* __restrict__ Out, int nsplit) {
  int bid = blockIdx.x;
  int qt = bid & 3, bh = bid >> 2;
  int h = bh % 12, b = bh / 12;
  int tid = threadIdx.x;
  int r = tid >> 2, dc = tid & 3;
  const float* mlb = Ml + (size_t)(bh * 4 + qt) * nsplit * 128;
  float M = -1e30f;
  for (int s = 0; s < nsplit; s++) M = fmaxf(M, mlb[s * 128 + r]);
  float L = 0.f;
  float accv[16];
#pragma unroll
  for (int i = 0; i < 16; i++) accv[i] = 0.f;
  const u16* pb = Part + (size_t)(bh * 4 + qt) * nsplit * 4096 + r * 64 + dc * 16;
  for (int s = 0; s < nsplit; s++) {
    float wgt = __expf(mlb[s * 128 + r] - M);
    L += wgt * mlb[s * 128 + 64 + r];
    u16 tmp[16];
    *(uint4*)tmp = *(const uint4*)(pb + s * 4096);
    *(uint4*)(tmp + 8) = *(const uint4*)(pb + s * 4096 + 8);
#pragma unroll
    for (int i = 0; i < 16; i++) accv[i] += wgt * bf2f(tmp[i]);
  }
  float inv = 1.f / L;
  u16 ot[16];
#pragma unroll
  for (int i = 0; i < 16; i++) ot[i] = f2bf(accv[i] * inv);
  u16* ob = Out + ((size_t)(b * 256 + qt * 64 + r)) * 768 + h * 64 + dc * 16;
  *(uint4*)ob = *(uint4*)ot;
  *(uint4*)(ob + 8) = *(uint4*)(ot + 8);
}

// ---------------- LayerNorm ----------------
__global__ __launch_bounds__(256) void ln_kernel(const float* __restrict__ X,
                                                 const float* __restrict__ sc,
                                                 const float* __restrict__ bi,
                                                 u16* __restrict__ Hout) {
  int row = blockIdx.x;
  int tid = threadIdx.x;
  const float* x = X + (size_t)row * 768;
  float v0 = x[tid], v1 = x[tid + 256], v2 = x[tid + 512];
  float s = v0 + v1 + v2;
  float q = v0 * v0 + v1 * v1 + v2 * v2;
#pragma unroll
  for (int m = 1; m < 64; m <<= 1) {
    s += __shfl_xor(s, m, 64);
    q += __shfl_xor(q, m, 64);
  }
  __shared__ float rs[4], rq[4];
  if ((tid & 63) == 0) { rs[tid >> 6] = s; rq[tid >> 6] = q; }
  __syncthreads();
  s = rs[0] + rs[1] + rs[2] + rs[3];
  q = rq[0] + rq[1] + rq[2] + rq[3];
  float mu = s * (1.f / 768.f);
  float var = q * (1.f / 768.f) - mu * mu;
  float rstd = rsqrtf(var + 1e-5f);
  u16* ho = Hout + (size_t)row * 768;
  ho[tid]       = f2bf((v0 - mu) * rstd * sc[tid]       + bi[tid]);
  ho[tid + 256] = f2bf((v1 - mu) * rstd * sc[tid + 256] + bi[tid + 256]);
  ho[tid + 512] = f2bf((v2 - mu) * rstd * sc[tid + 512] + bi[tid + 512]);
}

__global__ __launch_bounds__(256) void copy4_kernel(const float* __restrict__ src,
                                                    float* __restrict__ dst, int n4) {
  int i = blockIdx.x * 256 + threadIdx.x;
  if (i < n4) ((float4*)dst)[i] = ((const float4*)src)[i];
}

// =====================================================================
extern "C" void kernel_launch(void* const* d_in, const int* in_sizes, int n_in,
                              void* d_out, int out_size, void* d_ws, size_t ws_size,
                              hipStream_t stream) {
  const float* pc        = (const float*)d_in[0];
  const float* feats     = (const float*)d_in[1];
  const float* query     = (const float*)d_in[2];
  const float* in_W      = (const float*)d_in[3];
  const float* in_b      = (const float*)d_in[4];
  const float* ca_qkv_W  = (const float*)d_in[5];
  const float* ca_qkv_b  = (const float*)d_in[6];
  const float* ca_proj_W = (const float*)d_in[7];
  const float* ca_proj_b = (const float*)d_in[8];
  const float* ln1_s     = (const float*)d_in[9];
  const float* ln1_b     = (const float*)d_in[10];
  const float* qkv_W     = (const float*)d_in[11];
  const float* qkv_b     = (const float*)d_in[12];
  const float* proj_W    = (const float*)d_in[13];
  const float* proj_b    = (const float*)d_in[14];
  const float* ln2_s     = (const float*)d_in[15];
  const float* ln2_b     = (const float*)d_in[16];
  const float* fc_W      = (const float*)d_in[17];
  const float* fc_b      = (const float*)d_in[18];
  const float* fc2_W     = (const float*)d_in[19];
  const float* fc2_b     = (const float*)d_in[20];

  char* base = (char*)d_ws;
  size_t off = 0;
  auto alloc = [&](size_t bytes) -> char* {
    char* p = base + off;
    off += (bytes + 255) & ~(size_t)255;
    return p;
  };

  // ---- fixed region (~41 MB) ----
  u16* Wq      = (u16*)alloc(768 * 64 * 2);
  u16* Wquery  = (u16*)alloc(256 * 768 * 2);
  u16* Wcaqkv  = (u16*)alloc(2304 * 768 * 2);
  u16* Wcaproj = (u16*)alloc(768 * 768 * 2);
  u16* Wlqkv   = (u16*)alloc(2304 * 768 * 2);
  u16* Wlproj  = (u16*)alloc(768 * 768 * 2);
  u16* Wlfc    = (u16*)alloc(3072 * 768 * 2);
  u16* Wlfc2   = (u16*)alloc(768 * 3072 * 2);
  u16* qc      = (u16*)alloc(256 * 768 * 2);
  u16* attn    = (u16*)alloc((size_t)2048 * 768 * 2);
  u16* hbuf    = (u16*)alloc((size_t)2048 * 768 * 2);
  // union region: layers (qkvb 9.44MB + VtS 3.15MB | fc1 12.58MB); cross (Part 12.58 + Ml 0.79)
  char* uni    = alloc(13369344);
  u16* qkvb    = (u16*)uni;
  u16* VtS     = (u16*)(uni + 9437184);
  u16* fc1     = (u16*)uni;
  u16* Part    = (u16*)uni;
  float* Ml    = (float*)(uni + 12582912);

  // ---- adaptive cross-attn chunking ----
  size_t fixed_end = off;
  // per batch: emb 0.5MB + data 6.29MB + kvbK 6.29MB + VtC 6.29MB
  size_t per_b = (size_t)4096 * 64 * 2 + 3 * ((size_t)4096 * 768 * 2);
  int CB;
  if (fixed_end + 8 * per_b + 4096 <= ws_size) CB = 8;
  else if (fixed_end + 2 * per_b + 4096 <= ws_size) CB = 2;
  else CB = 1;

  u16* emb   = (u16*)alloc((size_t)CB * 4096 * 64 * 2);
  u16* dataB = (u16*)alloc((size_t)CB * 4096 * 768 * 2);
  u16* kvbK  = (u16*)alloc((size_t)CB * 4096 * 768 * 2);
  u16* VtC   = (u16*)alloc((size_t)CB * 4096 * 768 * 2);

  float* latents = (float*)d_out;  // (2048 x 768) fp32
  const float scale2 = 0.125f;     // SCALE^2 = 1/sqrt(D_HEAD)

  // --- upfront conversions ---
  {
    int n0 = 256 * 768 / 4, n1 = 2304 * 768 / 4, n2 = 768 * 768 / 4;
    cvt4_kernel<<<(n0 + n1 + n2 + 255) / 256, 256, 0, stream>>>(
        query, Wquery, n0, ca_qkv_W, Wcaqkv, n1, ca_proj_W, Wcaproj, n2,
        nullptr, nullptr, 0);
  }
  pad_inw_kernel<<<192, 256, 0, stream>>>(in_W, Wq);

  // --- latent q projection ---
  gemm_t<64, 64, 2, 2, 0><<<dim3(4, 12), 256, 0, stream>>>(
      Wquery, Wcaqkv, ca_qkv_b, nullptr, nullptr, qc,
      256, 768, 768, 768, 0, nullptr, 0, 0, 0);

  // --- cross-attention, chunked over batches ---
  int nchunk = 8 / CB;
  for (int c = 0; c < nchunk; ++c) {
    int Mc = CB * 4096;
    const float* pc_c = pc + (size_t)c * Mc * 3;
    const float* ft_c = feats + (size_t)c * Mc * 3;
    embed_kernel<<<Mc / 4, 256, 0, stream>>>(pc_c, ft_c, emb);
    gemm_t<128, 128, 2, 2, 0><<<dim3(Mc / 128, 6), 256, 0, stream>>>(
        emb, Wq, in_b, nullptr, nullptr, dataB,
        Mc, 768, 768, 64, 0, nullptr, 0, 0, 0);
    // KV projection: y<6 -> K-half (normal, into kvbK stride 768);
    //                y>=6 -> V-half transposed directly into VtC[b*768+h*64+d][4096]
    gemm_t<128, 128, 2, 2, 1><<<dim3(Mc / 128, 12), 256, 0, stream>>>(
        dataB, Wcaqkv + (size_t)768 * 768, ca_qkv_b + 768, nullptr, nullptr, kvbK,
        Mc, 1536, 768, 768, 0, VtC, 6, 4096, 12);
    flash_kernel<<<CB * 12 * 16, 256, 0, stream>>>(
        qc, 0L, 768, 64, kvbK, (long)4096 * 768, 768, 64, VtC,
        nullptr, Part, Ml, 4096, 4, 1024, scale2);
    freduce_kernel<<<CB * 48, 256, 0, stream>>>(
        Part, Ml, attn + (size_t)c * CB * 256 * 768, 4);
  }
  gemm_t<64, 64, 2, 2, 0><<<dim3(32, 12), 256, 0, stream>>>(
      attn, Wcaproj, ca_proj_b, nullptr, latents, nullptr,
      2048, 768, 768, 768, 0, nullptr, 0, 0, 0);

  // --- transformer layers ---
  for (int l = 0; l < 8; ++l) {
    {
      int n0 = 2304 * 768 / 4, n1 = 768 * 768 / 4, n2 = 3072 * 768 / 4, n3 = n2;
      cvt4_kernel<<<(n0 + n1 + n2 + n3 + 255) / 256, 256, 0, stream>>>(
          qkv_W + (size_t)l * 2304 * 768, Wlqkv, n0,
          proj_W + (size_t)l * 768 * 768, Wlproj, n1,
          fc_W + (size_t)l * 3072 * 768, Wlfc, n2,
          fc2_W + (size_t)l * 768 * 3072, Wlfc2, n3);
    }
    ln_kernel<<<2048, 256, 0, stream>>>(latents, ln1_s + l * 768, ln1_b + l * 768, hbuf);
    gemm_t<64, 128, 1, 4, 0><<<dim3(32, 18), 256, 0, stream>>>(
        hbuf, Wlqkv, qkv_b + l * 2304, nullptr, nullptr, qkvb,
        2048, 2304, 2304, 768, 0, nullptr, 0, 0, 0);
    repack_vt_kernel<<<384, 256, 0, stream>>>(qkvb, (long)256 * 2304, 2304, 128, 192, VtS, 256);
    flash_kernel<<<384, 256, 0, stream>>>(
        qkvb, (long)256 * 2304, 2304, 192, qkvb + 64, (long)256 * 2304, 2304, 192,
        VtS, attn, nullptr, nullptr, 256, 1, 256, scale2);
    gemm_t<64, 64, 2, 2, 0><<<dim3(32, 12), 256, 0, stream>>>(
        attn, Wlproj, proj_b + l * 768, latents, latents, nullptr,
        2048, 768, 768, 768, 0, nullptr, 0, 0, 0);
    ln_kernel<<<2048, 256, 0, stream>>>(latents, ln2_s + l * 768, ln2_b + l * 768, hbuf);
    gemm_t<64, 128, 1, 4, 0><<<dim3(32, 24), 256, 0, stream>>>(
        hbuf, Wlfc, fc_b + l * 3072, nullptr, nullptr, fc1,
        2048, 3072, 3072, 768, 1, nullptr, 0, 0, 0);
    gemm_t<64, 64, 2, 2, 0><<<dim3(32, 12), 256, 0, stream>>>(
        fc1, Wlfc2, fc2_b + l * 768, latents, latents, nullptr,
        2048, 768, 768, 3072, 0, nullptr, 0, 0, 0);
  }

  // --- second output: pc passthrough ---
  copy4_kernel<<<96, 256, 0, stream>>>(pc, (float*)d_out + (size_t)2048 * 768, 98304 / 4);
}

// Round 5
// 1411.286 us; speedup vs baseline: 1.6260x; 1.0591x over previous
//
#include <hip/hip_runtime.h>
#include <stdint.h>

typedef unsigned short u16;
typedef __bf16 bf16x8 __attribute__((ext_vector_type(8)));
typedef float f32x4 __attribute__((ext_vector_type(4)));

#define DEVINL __device__ __forceinline__

DEVINL u16 f2bf(float f) {
  union { float f; unsigned u; } c; c.f = f;
  unsigned u = c.u + 0x7FFFu + ((c.u >> 16) & 1u);
  return (u16)(u >> 16);
}

DEVINL float bf2f(u16 v) {
  union { unsigned u; float f; } c; c.u = (unsigned)v << 16;
  return c.f;
}

DEVINL void gl2lds16(const void* g, void* l) {
  __builtin_amdgcn_global_load_lds(
      (const __attribute__((address_space(1))) unsigned int*)g,
      (__attribute__((address_space(3))) unsigned int*)l, 16, 0, 0);
}

// ---------------- fused 4-segment fp32 -> bf16 conversion ----------------
__global__ __launch_bounds__(256) void cvt4_kernel(
    const float* __restrict__ s0, u16* __restrict__ d0, int n0,
    const float* __restrict__ s1, u16* __restrict__ d1, int n1,
    const float* __restrict__ s2, u16* __restrict__ d2, int n2,
    const float* __restrict__ s3, u16* __restrict__ d3, int n3) {
  int i = blockIdx.x * 256 + threadIdx.x;
  const float* s; u16* d;
  if (i < n0) { s = s0; d = d0; }
  else {
    i -= n0;
    if (i < n1) { s = s1; d = d1; }
    else {
      i -= n1;
      if (i < n2) { s = s2; d = d2; }
      else {
        i -= n2;
        if (i >= n3) return;
        s = s3; d = d3;
      }
    }
  }
  float4 v = ((const float4*)s)[i];
  unsigned a = (unsigned)f2bf(v.x) | ((unsigned)f2bf(v.y) << 16);
  unsigned b = (unsigned)f2bf(v.z) | ((unsigned)f2bf(v.w) << 16);
  ((uint2*)d)[i] = make_uint2(a, b);
}

// in_W (768x54) -> bf16 transposed (64x768), rows j>=54 zero
__global__ __launch_bounds__(256) void pad_inwT_kernel(const float* __restrict__ src,
                                                       u16* __restrict__ dst) {
  int t = blockIdx.x * 256 + threadIdx.x;  // 64*768
  if (t >= 64 * 768) return;
  int j = t / 768, o = t - j * 768;
  dst[t] = (j < 54) ? f2bf(src[o * 54 + j]) : (u16)0;
}

// b'[m] = sum_o ca_qkv_W[768+m][o] * in_b[o] + ca_qkv_b[768+m], m in [0,1536)
__global__ __launch_bounds__(256) void bprime_kernel(const float* __restrict__ caW,
                                                     const float* __restrict__ caB,
                                                     const float* __restrict__ inb,
                                                     float* __restrict__ bp) {
  int w = threadIdx.x >> 6, lane = threadIdx.x & 63;
  int m = blockIdx.x * 4 + w;
  const float* row = caW + (size_t)(768 + m) * 768;
  float s = 0.f;
#pragma unroll
  for (int k = 0; k < 12; k++) s += row[lane + k * 64] * inb[lane + k * 64];
#pragma unroll
  for (int msk = 32; msk >= 1; msk >>= 1) s += __shfl_xor(s, msk, 64);
  if (lane == 0) bp[m] = s + caB[768 + m];
}

// ---------------- fourier embed ----------------
__global__ __launch_bounds__(256) void embed_kernel(const float* __restrict__ pc,
                                                    const float* __restrict__ feats,
                                                    u16* __restrict__ emb) {
  int t = blockIdx.x * 256 + threadIdx.x;
  int p = t >> 6, c = t & 63;
  float v = 0.f;
  if (c < 3) {
    v = pc[p * 3 + c];
  } else if (c < 27) {
    int i = c - 3;
    float f = (float)(1 << (i & 7));
    v = sinf(pc[p * 3 + (i >> 3)] * f);
  } else if (c < 51) {
    int i = c - 27;
    float f = (float)(1 << (i & 7));
    v = cosf(pc[p * 3 + (i >> 3)] * f);
  } else if (c < 54) {
    v = feats[p * 3 + (c - 51)];
  }
  emb[t] = f2bf(v);
}

// ---------------- templated GEMM ----------------
// MODE 0: operand-swapped MFMA -> lane=m, regs=4 consecutive n -> vectorized epilogue.
// MODE 1: blocks y<vy as MODE0; y>=vy keep original order, write transposed into
//         vt[b*768+(n-vy*TN)][s] (regs = 4 consecutive m = consecutive s).
template <int TM, int TN, int WR, int WC, int MODE>
__global__ __launch_bounds__(256) void gemm_t(
    const u16* __restrict__ A, const u16* __restrict__ Bw,
    const float* __restrict__ bias, const float* __restrict__ resid,
    float* __restrict__ outF, u16* __restrict__ outB,
    int M, int N, int Nout, int K, int gelu,
    u16* __restrict__ vt, int vy, int skvt, int bsh) {
  constexpr int IM = TM / WR / 16;
  constexpr int IN = TN / WC / 16;
  __shared__ u16 As[TM * 32];
  __shared__ u16 Bs[TN * 32];
  const int tid = threadIdx.x;
  const int lane = tid & 63, w = tid >> 6;
  const int l15 = lane & 15, quad = lane >> 4;
  const int mblk = blockIdx.x * TM, nblk = blockIdx.y * TN;
  const int wm = (w % WR) * (TM / WR);
  const int wn = (w / WR) * (TN / WC);

  f32x4 acc[IM][IN];
#pragma unroll
  for (int i = 0; i < IM; i++)
#pragma unroll
    for (int j = 0; j < IN; j++) acc[i][j] = f32x4{0.f, 0.f, 0.f, 0.f};

  const bool tv = (MODE == 1) && ((int)blockIdx.y >= vy);

  if (!tv) {
    for (int k0 = 0; k0 < K; k0 += 32) {
#pragma unroll
      for (int s = tid; s < TM * 4; s += 256) {
        int row = s >> 2, c8 = (s & 3) << 3;
        gl2lds16(A + (size_t)(mblk + row) * K + (k0 + c8), &As[s * 8]);
      }
#pragma unroll
      for (int s = tid; s < TN * 4; s += 256) {
        int row = s >> 2, c8 = (s & 3) << 3;
        gl2lds16(Bw + (size_t)(nblk + row) * K + (k0 + c8), &Bs[s * 8]);
      }
      __syncthreads();
      bf16x8 af[IM], bfr[IN];
#pragma unroll
      for (int i = 0; i < IM; i++)
        af[i] = *(const bf16x8*)&As[(wm + i * 16 + l15) * 32 + quad * 8];
#pragma unroll
      for (int j = 0; j < IN; j++)
        bfr[j] = *(const bf16x8*)&Bs[(wn + j * 16 + l15) * 32 + quad * 8];
#pragma unroll
      for (int i = 0; i < IM; i++)
#pragma unroll
        for (int j = 0; j < IN; j++)
          acc[i][j] = __builtin_amdgcn_mfma_f32_16x16x32_bf16(bfr[j], af[i], acc[i][j], 0, 0, 0);
      __syncthreads();
    }
#pragma unroll
    for (int i = 0; i < IM; i++) {
      int m = mblk + wm + i * 16 + l15;
#pragma unroll
      for (int j = 0; j < IN; j++) {
        int n0 = nblk + wn + j * 16 + quad * 4;
        float4 bv = bias ? *(const float4*)&bias[n0] : make_float4(0.f, 0.f, 0.f, 0.f);
        float v0 = acc[i][j][0] + bv.x;
        float v1 = acc[i][j][1] + bv.y;
        float v2 = acc[i][j][2] + bv.z;
        float v3 = acc[i][j][3] + bv.w;
        if (gelu) {
          v0 = 0.5f * v0 * (1.0f + erff(v0 * 0.70710678118f));
          v1 = 0.5f * v1 * (1.0f + erff(v1 * 0.70710678118f));
          v2 = 0.5f * v2 * (1.0f + erff(v2 * 0.70710678118f));
          v3 = 0.5f * v3 * (1.0f + erff(v3 * 0.70710678118f));
        }
        size_t idx = (size_t)m * Nout + n0;
        if (resid) {
          float4 rv = *(const float4*)&resid[idx];
          v0 += rv.x; v1 += rv.y; v2 += rv.z; v3 += rv.w;
        }
        if (outF) {
          float4 ov = {v0, v1, v2, v3};
          *(float4*)&outF[idx] = ov;
        }
        if (outB) {
          unsigned lo = (unsigned)f2bf(v0) | ((unsigned)f2bf(v1) << 16);
          unsigned hi = (unsigned)f2bf(v2) | ((unsigned)f2bf(v3) << 16);
          *(uint2*)&outB[idx] = make_uint2(lo, hi);
        }
      }
    }
  } else {
    for (int k0 = 0; k0 < K; k0 += 32) {
#pragma unroll
      for (int s = tid; s < TM * 4; s += 256) {
        int row = s >> 2, c8 = (s & 3) << 3;
        gl2lds16(A + (size_t)(mblk + row) * K + (k0 + c8), &As[s * 8]);
      }
#pragma unroll
      for (int s = tid; s < TN * 4; s += 256) {
        int row = s >> 2, c8 = (s & 3) << 3;
        gl2lds16(Bw + (size_t)(nblk + row) * K + (k0 + c8), &Bs[s * 8]);
      }
      __syncthreads();
      bf16x8 af[IM], bfr[IN];
#pragma unroll
      for (int i = 0; i < IM; i++)
        af[i] = *(const bf16x8*)&As[(wm + i * 16 + l15) * 32 + quad * 8];
#pragma unroll
      for (int j = 0; j < IN; j++)
        bfr[j] = *(const bf16x8*)&Bs[(wn + j * 16 + l15) * 32 + quad * 8];
#pragma unroll
      for (int i = 0; i < IM; i++)
#pragma unroll
        for (int j = 0; j < IN; j++)
          acc[i][j] = __builtin_amdgcn_mfma_f32_16x16x32_bf16(af[i], bfr[j], acc[i][j], 0, 0, 0);
      __syncthreads();
    }
    int msk = (1 << bsh) - 1;
#pragma unroll
    for (int j = 0; j < IN; j++) {
      int n = nblk + wn + j * 16 + l15;
      float bv = bias ? bias[n] : 0.f;
      int nv = n - vy * TN;
#pragma unroll
      for (int i = 0; i < IM; i++) {
        int m0 = mblk + wm + i * 16 + quad * 4;
        int b = m0 >> bsh;
        int s0 = m0 & msk;
        float v0 = acc[i][j][0] + bv;
        float v1 = acc[i][j][1] + bv;
        float v2 = acc[i][j][2] + bv;
        float v3 = acc[i][j][3] + bv;
        unsigned lo = (unsigned)f2bf(v0) | ((unsigned)f2bf(v1) << 16);
        unsigned hi = (unsigned)f2bf(v2) | ((unsigned)f2bf(v3) << 16);
        size_t addr = (size_t)(b * 768 + nv) * skvt + s0;
        *(uint2*)&vt[addr] = make_uint2(lo, hi);
      }
    }
  }
}

// ---------------- V^T repack (layer self-attn only) ----------------
__global__ __launch_bounds__(256) void repack_vt_kernel(
    const u16* __restrict__ In, long bstride, int rs, int voff, int hs,
    u16* __restrict__ Vt, int Skv) {
  __shared__ u16 tile[64 * 65];
  int nst = Skv >> 6;
  int bid = blockIdx.x;
  int st = bid % nst;
  int bh = bid / nst;
  int h = bh % 12, b = bh / 12;
  const u16* src = In + (size_t)b * bstride + (size_t)(st * 64) * rs + voff + h * hs;
  int tid = threadIdx.x;
#pragma unroll
  for (int p = 0; p < 2; p++) {
    int slot = tid + p * 256;
    int s = slot >> 3, d8 = (slot & 7) << 3;
    uint4 v = *(const uint4*)(src + (size_t)s * rs + d8);
    u16 tmp[8];
    *(uint4*)tmp = v;
#pragma unroll
    for (int j = 0; j < 8; j++) tile[s * 65 + d8 + j] = tmp[j];
  }
  __syncthreads();
  u16* dst = Vt + ((size_t)(b * 12 + h) * 64) * Skv + st * 64;
#pragma unroll
  for (int p = 0; p < 2; p++) {
    int slot = tid + p * 256;
    int d = slot >> 3, s8 = (slot & 7) << 3;
    u16 tmp[8];
#pragma unroll
    for (int j = 0; j < 8; j++) tmp[j] = tile[(s8 + j) * 65 + d];
    *(uint4*)(dst + (size_t)d * Skv + s8) = *(uint4*)tmp;
  }
}

// ---------------- flash attention (MFMA, online softmax, optional split-KV) ----------------
__global__ __launch_bounds__(256) void flash_kernel(
    const u16* __restrict__ Q, long qb, int qrs, int qhs,
    const u16* __restrict__ Kp, long kb, int krs, int khs,
    const u16* __restrict__ Vt, u16* __restrict__ Out,
    u16* __restrict__ Part, float* __restrict__ Ml,
    int Skv, int nsplit, int kvlen, float scale2) {
  __shared__ u16 Qs[64 * 64];
  __shared__ u16 Ks[64 * 64];
  __shared__ u16 Vs[64 * 64];
  __shared__ u16 Ps[64 * 72];

  const int tid = threadIdx.x;
  const int lane = tid & 63, w = tid >> 6;
  const int l15 = lane & 15, quad = lane >> 4;

  int bid = blockIdx.x;
  int per_bh = nsplit << 2;
  int bh = bid / per_bh;
  int rem = bid - bh * per_bh;
  int split = rem >> 2, qt = rem & 3;
  int h = bh % 12, b = bh / 12;

  const u16* Qbase = Q + (size_t)b * qb + (size_t)(qt * 64) * qrs + h * qhs;
  const u16* Kbase = Kp + (size_t)b * kb + (size_t)h * khs;
  const u16* Vbase = Vt + ((size_t)(b * 12 + h) * 64) * Skv;

#pragma unroll
  for (int p = 0; p < 2; ++p) {
    int slot = tid + p * 256;
    int row = slot >> 3, c = slot & 7;
    int cg = (c - row) & 7;
    gl2lds16(Qbase + (size_t)row * qrs + cg * 8, &Qs[slot * 8]);
  }
  __syncthreads();

  bf16x8 qa[2];
#pragma unroll
  for (int kk = 0; kk < 2; kk++)
    qa[kk] = *(const bf16x8*)&Qs[(w * 16 + l15) * 64 + ((kk * 4 + quad + l15) & 7) * 8];

  f32x4 zero = {0.f, 0.f, 0.f, 0.f};
  f32x4 O[4];
  float m_i[4], l_i[4];
#pragma unroll
  for (int d = 0; d < 4; d++) O[d] = zero;
#pragma unroll
  for (int r = 0; r < 4; r++) { m_i[r] = -1e30f; l_i[r] = 0.f; }

  int kt0 = split * kvlen;
  for (int kt = kt0; kt < kt0 + kvlen; kt += 64) {
#pragma unroll
    for (int p = 0; p < 2; ++p) {
      int slot = tid + p * 256;
      int row = slot >> 3, c = slot & 7;
      int cg = (c - row) & 7;
      gl2lds16(Kbase + (size_t)(kt + row) * krs + cg * 8, &Ks[slot * 8]);
      gl2lds16(Vbase + (size_t)row * Skv + kt + cg * 8, &Vs[slot * 8]);
    }
    __syncthreads();

    f32x4 S[4];
#pragma unroll
    for (int j = 0; j < 4; j++) S[j] = zero;
#pragma unroll
    for (int kk = 0; kk < 2; kk++) {
#pragma unroll
      for (int j = 0; j < 4; j++) {
        bf16x8 kf = *(const bf16x8*)&Ks[(j * 16 + l15) * 64 + ((kk * 4 + quad + l15) & 7) * 8];
        S[j] = __builtin_amdgcn_mfma_f32_16x16x32_bf16(qa[kk], kf, S[j], 0, 0, 0);
      }
    }
    float alpha[4];
#pragma unroll
    for (int r = 0; r < 4; r++) {
      float s0 = S[0][r] * scale2, s1 = S[1][r] * scale2;
      float s2 = S[2][r] * scale2, s3 = S[3][r] * scale2;
      S[0][r] = s0; S[1][r] = s1; S[2][r] = s2; S[3][r] = s3;
      float mx = fmaxf(fmaxf(s0, s1), fmaxf(s2, s3));
#pragma unroll
      for (int msk = 1; msk < 16; msk <<= 1) mx = fmaxf(mx, __shfl_xor(mx, msk, 64));
      float mnew = fmaxf(m_i[r], mx);
      float al = __expf(m_i[r] - mnew);
      m_i[r] = mnew;
      alpha[r] = al;
      float sum = 0.f;
#pragma unroll
      for (int j = 0; j < 4; j++) {
        float pv = __expf(S[j][r] - mnew);
        S[j][r] = pv;
        sum += pv;
      }
#pragma unroll
      for (int msk = 1; msk < 16; msk <<= 1) sum += __shfl_xor(sum, msk, 64);
      l_i[r] = l_i[r] * al + sum;
    }
#pragma unroll
    for (int j = 0; j < 4; j++)
#pragma unroll
      for (int r = 0; r < 4; r++)
        Ps[(w * 16 + quad * 4 + r) * 72 + j * 16 + l15] = f2bf(S[j][r]);
#pragma unroll
    for (int d = 0; d < 4; d++)
#pragma unroll
      for (int r = 0; r < 4; r++) O[d][r] *= alpha[r];
    __asm__ __volatile__("s_waitcnt lgkmcnt(0)" ::: "memory");
#pragma unroll
    for (int kk = 0; kk < 2; kk++) {
      bf16x8 pa = *(const bf16x8*)&Ps[(w * 16 + l15) * 72 + kk * 32 + quad * 8];
#pragma unroll
      for (int d = 0; d < 4; d++) {
        bf16x8 vf = *(const bf16x8*)&Vs[(d * 16 + l15) * 64 + ((kk * 4 + quad + l15) & 7) * 8];
        O[d] = __builtin_amdgcn_mfma_f32_16x16x32_bf16(pa, vf, O[d], 0, 0, 0);
      }
    }
    __syncthreads();
  }

  if (nsplit == 1) {
    u16* Ob = Out + ((size_t)(b * 256 + qt * 64 + w * 16 + quad * 4)) * 768 + h * 64 + l15;
#pragma unroll
    for (int d = 0; d < 4; d++)
#pragma unroll
      for (int r = 0; r < 4; r++) {
        float v = O[d][r] / l_i[r];
        Ob[(size_t)r * 768 + d * 16] = f2bf(v);
      }
  } else {
    u16* Pb = Part + ((size_t)(bh * 4 + qt) * nsplit + split) * 4096;
    int rowb = w * 16 + quad * 4;
#pragma unroll
    for (int d = 0; d < 4; d++)
#pragma unroll
      for (int r = 0; r < 4; r++)
        Pb[(rowb + r) * 64 + d * 16 + l15] = f2bf(O[d][r]);
    if (l15 == 0) {
      float* MlB = Ml + ((size_t)(bh * 4 + qt) * nsplit + split) * 128;
#pragma unroll
      for (int r = 0; r < 4; r++) {
        MlB[rowb + r] = m_i[r];
        MlB[64 + rowb + r] = l_i[r];
      }
    }
  }
}

// ---------------- split-KV reduce ----------------
__global__ __launch_bounds__(256) void freduce_kernel(
    const u16* __restrict__ Part, const float* __restrict__ Ml,
    u16* __restrict__ Out, int nsplit) {
  int bid = blockIdx.x;
  int qt = bid & 3, bh = bid >> 2;
  int h = bh % 12, b = bh / 12;
  int tid = threadIdx.x;
  int r = tid >> 2, dc = tid & 3;
  const float* mlb = Ml + (size_t)(bh * 4 + qt) * nsplit * 128;
  float M = -1e30f;
  for (int s = 0; s < nsplit; s++) M = fmaxf(M, mlb[s * 128 + r]);
  float L = 0.f;
  float accv[16];
#pragma unroll
  for (int i = 0; i < 16; i++) accv[i] = 0.f;
  const u16* pb = Part + (size_t)(bh * 4 + qt) * nsplit * 4096 + r * 64 + dc * 16;
  for (int s = 0; s < nsplit; s++) {
    float wgt = __expf(mlb[s * 128 + r] - M);
    L += wgt * mlb[s * 128 + 64 + r];
    u16 tmp[16];
    *(uint4*)tmp = *(const uint4*)(pb + s * 4096);
    *(uint4*)(tmp + 8) = *(const uint4*)(pb + s * 4096 + 8);
#pragma unroll
    for (int i = 0; i < 16; i++) accv[i] += wgt * bf2f(tmp[i]);
  }
  float inv = 1.f / L;
  u16 ot[16];
#pragma unroll
  for (int i = 0; i < 16; i++) ot[i] = f2bf(accv[i] * inv);
  u16* ob = Out + ((size_t)(b * 256 + qt * 64 + r)) * 768 + h * 64 + dc * 16;
  *(uint4*)ob = *(uint4*)ot;
  *(uint4*)(ob + 8) = *(uint4*)(ot + 8);
}

// ---------------- LayerNorm ----------------
__global__ __launch_bounds__(256) void ln_kernel(const float* __restrict__ X,
                                                 const float* __restrict__ sc,
                                                 const float* __restrict__ bi,
                                                 u16* __restrict__ Hout) {
  int row = blockIdx.x;
  int tid = threadIdx.x;
  const float* x = X + (size_t)row * 768;
  float v0 = x[tid], v1 = x[tid + 256], v2 = x[tid + 512];
  float s = v0 + v1 + v2;
  float q = v0 * v0 + v1 * v1 + v2 * v2;
#pragma unroll
  for (int m = 1; m < 64; m <<= 1) {
    s += __shfl_xor(s, m, 64);
    q += __shfl_xor(q, m, 64);
  }
  __shared__ float rs[4], rq[4];
  if ((tid & 63) == 0) { rs[tid >> 6] = s; rq[tid >> 6] = q; }
  __syncthreads();
  s = rs[0] + rs[1] + rs[2] + rs[3];
  q = rq[0] + rq[1] + rq[2] + rq[3];
  float mu = s * (1.f / 768.f);
  float var = q * (1.f / 768.f) - mu * mu;
  float rstd = rsqrtf(var + 1e-5f);
  u16* ho = Hout + (size_t)row * 768;
  ho[tid]       = f2bf((v0 - mu) * rstd * sc[tid]       + bi[tid]);
  ho[tid + 256] = f2bf((v1 - mu) * rstd * sc[tid + 256] + bi[tid + 256]);
  ho[tid + 512] = f2bf((v2 - mu) * rstd * sc[tid + 512] + bi[tid + 512]);
}

__global__ __launch_bounds__(256) void copy4_kernel(const float* __restrict__ src,
                                                    float* __restrict__ dst, int n4) {
  int i = blockIdx.x * 256 + threadIdx.x;
  if (i < n4) ((float4*)dst)[i] = ((const float4*)src)[i];
}

// =====================================================================
extern "C" void kernel_launch(void* const* d_in, const int* in_sizes, int n_in,
                              void* d_out, int out_size, void* d_ws, size_t ws_size,
                              hipStream_t stream) {
  const float* pc        = (const float*)d_in[0];
  const float* feats     = (const float*)d_in[1];
  const float* query     = (const float*)d_in[2];
  const float* in_W      = (const float*)d_in[3];
  const float* in_b      = (const float*)d_in[4];
  const float* ca_qkv_W  = (const float*)d_in[5];
  const float* ca_qkv_b  = (const float*)d_in[6];
  const float* ca_proj_W = (const float*)d_in[7];
  const float* ca_proj_b = (const float*)d_in[8];
  const float* ln1_s     = (const float*)d_in[9];
  const float* ln1_b     = (const float*)d_in[10];
  const float* qkv_W     = (const float*)d_in[11];
  const float* qkv_b     = (const float*)d_in[12];
  const float* proj_W    = (const float*)d_in[13];
  const float* proj_b    = (const float*)d_in[14];
  const float* ln2_s     = (const float*)d_in[15];
  const float* ln2_b     = (const float*)d_in[16];
  const float* fc_W      = (const float*)d_in[17];
  const float* fc_b      = (const float*)d_in[18];
  const float* fc2_W     = (const float*)d_in[19];
  const float* fc2_b     = (const float*)d_in[20];

  char* base = (char*)d_ws;
  size_t off = 0;
  auto alloc = [&](size_t bytes) -> char* {
    char* p = base + off;
    off += (bytes + 255) & ~(size_t)255;
    return p;
  };

  // ---- fixed region (~25.5 MB) ----
  u16* WqT     = (u16*)alloc(64 * 768 * 2);        // in_W^T bf16, zero-padded
  u16* Wquery  = (u16*)alloc(256 * 768 * 2);
  u16* Wcaqkv  = (u16*)alloc(2304 * 768 * 2);
  u16* Wcaproj = (u16*)alloc(768 * 768 * 2);
  u16* Wkp     = (u16*)alloc(1536 * 64 * 2);       // W' = W_kv @ in_W (bf16)
  float* bprime = (float*)alloc(1536 * 4);         // b' = W_kv @ in_b + b_kv
  u16* qc      = (u16*)alloc(256 * 768 * 2);
  u16* attn    = (u16*)alloc((size_t)2048 * 768 * 2);
  u16* hbuf    = (u16*)alloc((size_t)2048 * 768 * 2);
  // union: layers (qkvb 9.44M + VtS 3.15M | fc1 12.58M); cross (Part 12.58M + Ml 0.79M)
  char* uni    = alloc(13369344);
  u16* qkvb    = (u16*)uni;
  u16* VtS     = (u16*)(uni + 9437184);
  u16* fc1     = (u16*)uni;
  u16* Part    = (u16*)uni;
  float* Ml    = (float*)(uni + 12582912);

  size_t fixed_end = off;
  const size_t wAllSz = (size_t)8 * (2304 * 768 + 768 * 768 + 2 * 3072 * 768) * 2;  // 113.2 MB
  auto crossSz = [](int cb) {
    return (size_t)cb * 4096 * 64 * 2 + 2 * ((size_t)cb * 4096 * 768 * 2);
  };

  bool allw; int CB;
  if (fixed_end + (wAllSz > crossSz(8) ? wAllSz : crossSz(8)) + 65536 <= ws_size) {
    allw = true;  CB = 8;   // X region: cross buffers (early) alias weights (late)
  } else if (fixed_end + 14155776 + crossSz(2) + 65536 <= ws_size) {
    allw = false; CB = 2;
  } else {
    allw = false; CB = 1;
  }

  u16 *WqkvB, *WprojB, *WfcB, *Wfc2B, *emb, *kvbK, *VtC;
  if (allw) {
    char* X = base + off;
    WqkvB  = (u16*)X;
    WprojB = WqkvB + (size_t)8 * 2304 * 768;
    WfcB   = WprojB + (size_t)8 * 768 * 768;
    Wfc2B  = WfcB + (size_t)8 * 3072 * 768;
    emb  = (u16*)X;                                        // aliased (cross phase only)
    kvbK = (u16*)(X + (size_t)CB * 4096 * 64 * 2);
    VtC  = (u16*)(X + (size_t)CB * 4096 * 64 * 2 + (size_t)CB * 4096 * 768 * 2);
  } else {
    WqkvB  = (u16*)alloc(2304 * 768 * 2);                  // rotating per-layer
    WprojB = (u16*)alloc(768 * 768 * 2);
    WfcB   = (u16*)alloc(3072 * 768 * 2);
    Wfc2B  = (u16*)alloc((size_t)768 * 3072 * 2);
    emb  = (u16*)alloc((size_t)CB * 4096 * 64 * 2);
    kvbK = (u16*)alloc((size_t)CB * 4096 * 768 * 2);
    VtC  = (u16*)alloc((size_t)CB * 4096 * 768 * 2);
  }

  float* latents = (float*)d_out;  // (2048 x 768) fp32
  const float scale2 = 0.125f;     // SCALE^2 = 1/sqrt(D_HEAD)

  // --- upfront conversions + fused-weight precompute ---
  {
    int n0 = 256 * 768 / 4, n1 = 2304 * 768 / 4, n2 = 768 * 768 / 4;
    cvt4_kernel<<<(n0 + n1 + n2 + 255) / 256, 256, 0, stream>>>(
        query, Wquery, n0, ca_qkv_W, Wcaqkv, n1, ca_proj_W, Wcaproj, n2,
        nullptr, nullptr, 0);
  }
  pad_inwT_kernel<<<192, 256, 0, stream>>>(in_W, WqT);
  // W' (1536x64) = W_kv (1536x768) @ in_W^T-rows (64x768)^T
  gemm_t<64, 64, 2, 2, 0><<<dim3(24, 1), 256, 0, stream>>>(
      Wcaqkv + (size_t)768 * 768, WqT, nullptr, nullptr, nullptr, Wkp,
      1536, 64, 64, 768, 0, nullptr, 0, 0, 0);
  bprime_kernel<<<384, 256, 0, stream>>>(ca_qkv_W, ca_qkv_b, in_b, bprime);

  // --- latent q projection ---
  gemm_t<64, 64, 2, 2, 0><<<dim3(4, 12), 256, 0, stream>>>(
      Wquery, Wcaqkv, ca_qkv_b, nullptr, nullptr, qc,
      256, 768, 768, 768, 0, nullptr, 0, 0, 0);

  // --- cross-attention, chunked over batches ---
  int nchunk = 8 / CB;
  for (int c = 0; c < nchunk; ++c) {
    int Mc = CB * 4096;
    const float* pc_c = pc + (size_t)c * Mc * 3;
    const float* ft_c = feats + (size_t)c * Mc * 3;
    embed_kernel<<<Mc / 4, 256, 0, stream>>>(pc_c, ft_c, emb);
    // fused KV projection (K=64): y<6 -> K-half into kvbK; y>=6 -> V transposed into VtC
    gemm_t<128, 128, 2, 2, 1><<<dim3(Mc / 128, 12), 256, 0, stream>>>(
        emb, Wkp, bprime, nullptr, nullptr, kvbK,
        Mc, 1536, 768, 64, 0, VtC, 6, 4096, 12);
    flash_kernel<<<CB * 12 * 16, 256, 0, stream>>>(
        qc, 0L, 768, 64, kvbK, (long)4096 * 768, 768, 64, VtC,
        nullptr, Part, Ml, 4096, 4, 1024, scale2);
    freduce_kernel<<<CB * 48, 256, 0, stream>>>(
        Part, Ml, attn + (size_t)c * CB * 256 * 768, 4);
  }
  gemm_t<64, 64, 2, 2, 0><<<dim3(32, 12), 256, 0, stream>>>(
      attn, Wcaproj, ca_proj_b, nullptr, latents, nullptr,
      2048, 768, 768, 768, 0, nullptr, 0, 0, 0);

  // --- all-layer weight conversion (one sweep; X region now dead for cross) ---
  if (allw) {
    int n0 = 8 * 2304 * 768 / 4, n1 = 8 * 768 * 768 / 4, n2 = 8 * 3072 * 768 / 4;
    cvt4_kernel<<<(n0 + n1 + 2 * n2 + 255) / 256, 256, 0, stream>>>(
        qkv_W, WqkvB, n0, proj_W, WprojB, n1, fc_W, WfcB, n2, fc2_W, Wfc2B, n2);
  }

  // --- transformer layers ---
  for (int l = 0; l < 8; ++l) {
    u16* Wlq  = allw ? WqkvB  + (size_t)l * 2304 * 768 : WqkvB;
    u16* Wlp  = allw ? WprojB + (size_t)l * 768 * 768  : WprojB;
    u16* Wlf  = allw ? WfcB   + (size_t)l * 3072 * 768 : WfcB;
    u16* Wlf2 = allw ? Wfc2B  + (size_t)l * 3072 * 768 : Wfc2B;
    if (!allw) {
      int n0 = 2304 * 768 / 4, n1 = 768 * 768 / 4, n2 = 3072 * 768 / 4;
      cvt4_kernel<<<(n0 + n1 + 2 * n2 + 255) / 256, 256, 0, stream>>>(
          qkv_W + (size_t)l * 2304 * 768, Wlq, n0,
          proj_W + (size_t)l * 768 * 768, Wlp, n1,
          fc_W + (size_t)l * 3072 * 768, Wlf, n2,
          fc2_W + (size_t)l * 768 * 3072, Wlf2, n2);
    }
    ln_kernel<<<2048, 256, 0, stream>>>(latents, ln1_s + l * 768, ln1_b + l * 768, hbuf);
    gemm_t<64, 128, 1, 4, 0><<<dim3(32, 18), 256, 0, stream>>>(
        hbuf, Wlq, qkv_b + l * 2304, nullptr, nullptr, qkvb,
        2048, 2304, 2304, 768, 0, nullptr, 0, 0, 0);
    repack_vt_kernel<<<384, 256, 0, stream>>>(qkvb, (long)256 * 2304, 2304, 128, 192, VtS, 256);
    flash_kernel<<<384, 256, 0, stream>>>(
        qkvb, (long)256 * 2304, 2304, 192, qkvb + 64, (long)256 * 2304, 2304, 192,
        VtS, attn, nullptr, nullptr, 256, 1, 256, scale2);
    gemm_t<64, 64, 2, 2, 0><<<dim3(32, 12), 256, 0, stream>>>(
        attn, Wlp, proj_b + l * 768, latents, latents, nullptr,
        2048, 768, 768, 768, 0, nullptr, 0, 0, 0);
    ln_kernel<<<2048, 256, 0, stream>>>(latents, ln2_s + l * 768, ln2_b + l * 768, hbuf);
    gemm_t<64, 128, 1, 4, 0><<<dim3(32, 24), 256, 0, stream>>>(
        hbuf, Wlf, fc_b + l * 3072, nullptr, nullptr, fc1,
        2048, 3072, 3072, 768, 1, nullptr, 0, 0, 0);
    gemm_t<64, 64, 2, 2, 0><<<dim3(32, 12), 256, 0, stream>>>(
        fc1, Wlf2, fc2_b + l * 768, latents, latents, nullptr,
        2048, 768, 768, 3072, 0, nullptr, 0, 0, 0);
  }

  // --- second output: pc passthrough ---
  copy4_kernel<<<96, 256, 0, stream>>>(pc, (float*)d_out + (size_t)2048 * 768, 98304 / 4);
}

// Round 6
// 1363.210 us; speedup vs baseline: 1.6833x; 1.0353x over previous
//
#include <hip/hip_runtime.h>
#include <stdint.h>

typedef unsigned short u16;
typedef __bf16 bf16x8 __attribute__((ext_vector_type(8)));
typedef float f32x4 __attribute__((ext_vector_type(4)));

#define DEVINL __device__ __forceinline__

DEVINL u16 f2bf(float f) {
  union { float f; unsigned u; } c; c.f = f;
  unsigned u = c.u + 0x7FFFu + ((c.u >> 16) & 1u);
  return (u16)(u >> 16);
}

DEVINL float bf2f(u16 v) {
  union { unsigned u; float f; } c; c.u = (unsigned)v << 16;
  return c.f;
}

// packed fp32x2 -> bf16x2 (HW instruction when available; RNE either way)
DEVINL unsigned pk2bf(float a, float b) {
#if __has_builtin(__builtin_amdgcn_cvt_pk_bf16_f32)
  auto r = __builtin_amdgcn_cvt_pk_bf16_f32(a, b);
  unsigned u;
  __builtin_memcpy(&u, &r, 4);
  return u;
#else
  return (unsigned)f2bf(a) | ((unsigned)f2bf(b) << 16);
#endif
}

DEVINL void gl2lds16(const void* g, void* l) {
  __builtin_amdgcn_global_load_lds(
      (const __attribute__((address_space(1))) unsigned int*)g,
      (__attribute__((address_space(3))) unsigned int*)l, 16, 0, 0);
}

// ---------------- fused 4-segment fp32 -> bf16 conversion ----------------
__global__ __launch_bounds__(256) void cvt4_kernel(
    const float* __restrict__ s0, u16* __restrict__ d0, int n0,
    const float* __restrict__ s1, u16* __restrict__ d1, int n1,
    const float* __restrict__ s2, u16* __restrict__ d2, int n2,
    const float* __restrict__ s3, u16* __restrict__ d3, int n3) {
  int i = blockIdx.x * 256 + threadIdx.x;
  const float* s; u16* d;
  if (i < n0) { s = s0; d = d0; }
  else {
    i -= n0;
    if (i < n1) { s = s1; d = d1; }
    else {
      i -= n1;
      if (i < n2) { s = s2; d = d2; }
      else {
        i -= n2;
        if (i >= n3) return;
        s = s3; d = d3;
      }
    }
  }
  float4 v = ((const float4*)s)[i];
  ((uint2*)d)[i] = make_uint2(pk2bf(v.x, v.y), pk2bf(v.z, v.w));
}

// in_W (768x54) -> bf16 transposed (64x768), rows j>=54 zero
__global__ __launch_bounds__(256) void pad_inwT_kernel(const float* __restrict__ src,
                                                       u16* __restrict__ dst) {
  int t = blockIdx.x * 256 + threadIdx.x;  // 64*768
  if (t >= 64 * 768) return;
  int j = t / 768, o = t - j * 768;
  dst[t] = (j < 54) ? f2bf(src[o * 54 + j]) : (u16)0;
}

// b'[m] = sum_o ca_qkv_W[768+m][o] * in_b[o] + ca_qkv_b[768+m]
__global__ __launch_bounds__(256) void bprime_kernel(const float* __restrict__ caW,
                                                     const float* __restrict__ caB,
                                                     const float* __restrict__ inb,
                                                     float* __restrict__ bp) {
  int w = threadIdx.x >> 6, lane = threadIdx.x & 63;
  int m = blockIdx.x * 4 + w;
  const float* row = caW + (size_t)(768 + m) * 768;
  float s = 0.f;
#pragma unroll
  for (int k = 0; k < 12; k++) s += row[lane + k * 64] * inb[lane + k * 64];
#pragma unroll
  for (int msk = 32; msk >= 1; msk >>= 1) s += __shfl_xor(s, msk, 64);
  if (lane == 0) bp[m] = s + caB[768 + m];
}

// ---------------- fourier embed ----------------
__global__ __launch_bounds__(256) void embed_kernel(const float* __restrict__ pc,
                                                    const float* __restrict__ feats,
                                                    u16* __restrict__ emb) {
  int t = blockIdx.x * 256 + threadIdx.x;
  int p = t >> 6, c = t & 63;
  float v = 0.f;
  if (c < 3) {
    v = pc[p * 3 + c];
  } else if (c < 27) {
    int i = c - 3;
    float f = (float)(1 << (i & 7));
    v = sinf(pc[p * 3 + (i >> 3)] * f);
  } else if (c < 51) {
    int i = c - 27;
    float f = (float)(1 << (i & 7));
    v = cosf(pc[p * 3 + (i >> 3)] * f);
  } else if (c < 54) {
    v = feats[p * 3 + (c - 51)];
  }
  emb[t] = f2bf(v);
}

// ---------------- templated GEMM ----------------
template <int TM, int TN, int WR, int WC, int MODE>
__global__ __launch_bounds__(256) void gemm_t(
    const u16* __restrict__ A, const u16* __restrict__ Bw,
    const float* __restrict__ bias, const float* __restrict__ resid,
    float* __restrict__ outF, u16* __restrict__ outB,
    int M, int N, int Nout, int K, int gelu,
    u16* __restrict__ vt, int vy, int skvt, int bsh) {
  constexpr int IM = TM / WR / 16;
  constexpr int IN = TN / WC / 16;
  __shared__ u16 As[TM * 32];
  __shared__ u16 Bs[TN * 32];
  const int tid = threadIdx.x;
  const int lane = tid & 63, w = tid >> 6;
  const int l15 = lane & 15, quad = lane >> 4;
  const int mblk = blockIdx.x * TM, nblk = blockIdx.y * TN;
  const int wm = (w % WR) * (TM / WR);
  const int wn = (w / WR) * (TN / WC);

  f32x4 acc[IM][IN];
#pragma unroll
  for (int i = 0; i < IM; i++)
#pragma unroll
    for (int j = 0; j < IN; j++) acc[i][j] = f32x4{0.f, 0.f, 0.f, 0.f};

  const bool tv = (MODE == 1) && ((int)blockIdx.y >= vy);

  if (!tv) {
    for (int k0 = 0; k0 < K; k0 += 32) {
#pragma unroll
      for (int s = tid; s < TM * 4; s += 256) {
        int row = s >> 2, c8 = (s & 3) << 3;
        gl2lds16(A + (size_t)(mblk + row) * K + (k0 + c8), &As[s * 8]);
      }
#pragma unroll
      for (int s = tid; s < TN * 4; s += 256) {
        int row = s >> 2, c8 = (s & 3) << 3;
        gl2lds16(Bw + (size_t)(nblk + row) * K + (k0 + c8), &Bs[s * 8]);
      }
      __syncthreads();
      bf16x8 af[IM], bfr[IN];
#pragma unroll
      for (int i = 0; i < IM; i++)
        af[i] = *(const bf16x8*)&As[(wm + i * 16 + l15) * 32 + quad * 8];
#pragma unroll
      for (int j = 0; j < IN; j++)
        bfr[j] = *(const bf16x8*)&Bs[(wn + j * 16 + l15) * 32 + quad * 8];
#pragma unroll
      for (int i = 0; i < IM; i++)
#pragma unroll
        for (int j = 0; j < IN; j++)
          acc[i][j] = __builtin_amdgcn_mfma_f32_16x16x32_bf16(bfr[j], af[i], acc[i][j], 0, 0, 0);
      __syncthreads();
    }
#pragma unroll
    for (int i = 0; i < IM; i++) {
      int m = mblk + wm + i * 16 + l15;
#pragma unroll
      for (int j = 0; j < IN; j++) {
        int n0 = nblk + wn + j * 16 + quad * 4;
        float4 bv = bias ? *(const float4*)&bias[n0] : make_float4(0.f, 0.f, 0.f, 0.f);
        float v0 = acc[i][j][0] + bv.x;
        float v1 = acc[i][j][1] + bv.y;
        float v2 = acc[i][j][2] + bv.z;
        float v3 = acc[i][j][3] + bv.w;
        if (gelu) {
          v0 = 0.5f * v0 * (1.0f + erff(v0 * 0.70710678118f));
          v1 = 0.5f * v1 * (1.0f + erff(v1 * 0.70710678118f));
          v2 = 0.5f * v2 * (1.0f + erff(v2 * 0.70710678118f));
          v3 = 0.5f * v3 * (1.0f + erff(v3 * 0.70710678118f));
        }
        size_t idx = (size_t)m * Nout + n0;
        if (resid) {
          float4 rv = *(const float4*)&resid[idx];
          v0 += rv.x; v1 += rv.y; v2 += rv.z; v3 += rv.w;
        }
        if (outF) {
          float4 ov = {v0, v1, v2, v3};
          *(float4*)&outF[idx] = ov;
        }
        if (outB) {
          *(uint2*)&outB[idx] = make_uint2(pk2bf(v0, v1), pk2bf(v2, v3));
        }
      }
    }
  } else {
    for (int k0 = 0; k0 < K; k0 += 32) {
#pragma unroll
      for (int s = tid; s < TM * 4; s += 256) {
        int row = s >> 2, c8 = (s & 3) << 3;
        gl2lds16(A + (size_t)(mblk + row) * K + (k0 + c8), &As[s * 8]);
      }
#pragma unroll
      for (int s = tid; s < TN * 4; s += 256) {
        int row = s >> 2, c8 = (s & 3) << 3;
        gl2lds16(Bw + (size_t)(nblk + row) * K + (k0 + c8), &Bs[s * 8]);
      }
      __syncthreads();
      bf16x8 af[IM], bfr[IN];
#pragma unroll
      for (int i = 0; i < IM; i++)
        af[i] = *(const bf16x8*)&As[(wm + i * 16 + l15) * 32 + quad * 8];
#pragma unroll
      for (int j = 0; j < IN; j++)
        bfr[j] = *(const bf16x8*)&Bs[(wn + j * 16 + l15) * 32 + quad * 8];
#pragma unroll
      for (int i = 0; i < IM; i++)
#pragma unroll
        for (int j = 0; j < IN; j++)
          acc[i][j] = __builtin_amdgcn_mfma_f32_16x16x32_bf16(af[i], bfr[j], acc[i][j], 0, 0, 0);
      __syncthreads();
    }
    int msk = (1 << bsh) - 1;
#pragma unroll
    for (int j = 0; j < IN; j++) {
      int n = nblk + wn + j * 16 + l15;
      float bv = bias ? bias[n] : 0.f;
      int nv = n - vy * TN;
#pragma unroll
      for (int i = 0; i < IM; i++) {
        int m0 = mblk + wm + i * 16 + quad * 4;
        int b = m0 >> bsh;
        int s0 = m0 & msk;
        float v0 = acc[i][j][0] + bv;
        float v1 = acc[i][j][1] + bv;
        float v2 = acc[i][j][2] + bv;
        float v3 = acc[i][j][3] + bv;
        size_t addr = (size_t)(b * 768 + nv) * skvt + s0;
        *(uint2*)&vt[addr] = make_uint2(pk2bf(v0, v1), pk2bf(v2, v3));
      }
    }
  }
}

// ---------------- V^T repack (layer self-attn only) ----------------
__global__ __launch_bounds__(256) void repack_vt_kernel(
    const u16* __restrict__ In, long bstride, int rs, int voff, int hs,
    u16* __restrict__ Vt, int Skv) {
  __shared__ u16 tile[64 * 65];
  int nst = Skv >> 6;
  int bid = blockIdx.x;
  int st = bid % nst;
  int bh = bid / nst;
  int h = bh % 12, b = bh / 12;
  const u16* src = In + (size_t)b * bstride + (size_t)(st * 64) * rs + voff + h * hs;
  int tid = threadIdx.x;
#pragma unroll
  for (int p = 0; p < 2; p++) {
    int slot = tid + p * 256;
    int s = slot >> 3, d8 = (slot & 7) << 3;
    uint4 v = *(const uint4*)(src + (size_t)s * rs + d8);
    u16 tmp[8];
    *(uint4*)tmp = v;
#pragma unroll
    for (int j = 0; j < 8; j++) tile[s * 65 + d8 + j] = tmp[j];
  }
  __syncthreads();
  u16* dst = Vt + ((size_t)(b * 12 + h) * 64) * Skv + st * 64;
#pragma unroll
  for (int p = 0; p < 2; p++) {
    int slot = tid + p * 256;
    int d = slot >> 3, s8 = (slot & 7) << 3;
    u16 tmp[8];
#pragma unroll
    for (int j = 0; j < 8; j++) tmp[j] = tile[(s8 + j) * 65 + d];
    *(uint4*)(dst + (size_t)d * Skv + s8) = *(uint4*)tmp;
  }
}

// ---------------- flash attention: swapped-S softmax (lane = q-row) ----------------
// bid map: qt slow dim so the nsplit*... replicas sharing KV land on the same XCD.
__global__ __launch_bounds__(256) void flash_kernel(
    const u16* __restrict__ Q, long qb, int qrs, int qhs,
    const u16* __restrict__ Kp, long kb, int krs, int khs,
    const u16* __restrict__ Vt, u16* __restrict__ Out,
    u16* __restrict__ Part, float* __restrict__ Ml,
    int Skv, int nsplit, int kvlen, int nbh, float scale2) {
  __shared__ u16 Qs[64 * 64];
  __shared__ u16 Ks[64 * 64];
  __shared__ u16 Vs[64 * 64];
  __shared__ u16 Ps[64 * 72];

  const int tid = threadIdx.x;
  const int lane = tid & 63, w = tid >> 6;
  const int l15 = lane & 15, quad = lane >> 4;

  int bid = blockIdx.x;
  int grp = nbh * nsplit;
  int qt = bid / grp;
  int rem = bid - qt * grp;
  int bh = rem / nsplit;
  int split = rem - bh * nsplit;
  int h = bh % 12, b = bh / 12;

  const u16* Qbase = Q + (size_t)b * qb + (size_t)(qt * 64) * qrs + h * qhs;
  const u16* Kbase = Kp + (size_t)b * kb + (size_t)h * khs;
  const u16* Vbase = Vt + ((size_t)(b * 12 + h) * 64) * Skv;

#pragma unroll
  for (int p = 0; p < 2; ++p) {
    int slot = tid + p * 256;
    int row = slot >> 3, c = slot & 7;
    int cg = (c - row) & 7;
    gl2lds16(Qbase + (size_t)row * qrs + cg * 8, &Qs[slot * 8]);
  }
  __syncthreads();

  bf16x8 qa[2];
#pragma unroll
  for (int kk = 0; kk < 2; kk++)
    qa[kk] = *(const bf16x8*)&Qs[(w * 16 + l15) * 64 + ((kk * 4 + quad + l15) & 7) * 8];

  f32x4 zero = {0.f, 0.f, 0.f, 0.f};
  f32x4 O[4];
#pragma unroll
  for (int d = 0; d < 4; d++) O[d] = zero;
  float m_i = -1e30f, l_i = 0.f;   // per-lane: q-row = w*16 + l15

  int kt0 = split * kvlen;
  for (int kt = kt0; kt < kt0 + kvlen; kt += 64) {
#pragma unroll
    for (int p = 0; p < 2; ++p) {
      int slot = tid + p * 256;
      int row = slot >> 3, c = slot & 7;
      int cg = (c - row) & 7;
      gl2lds16(Kbase + (size_t)(kt + row) * krs + cg * 8, &Ks[slot * 8]);
      gl2lds16(Vbase + (size_t)row * Skv + kt + cg * 8, &Vs[slot * 8]);
    }
    __syncthreads();

    // S^T = K x Q^T : row(reg) = kv-local = quad*4+r (+j*16), col(lane) = q-row
    f32x4 St[4];
#pragma unroll
    for (int j = 0; j < 4; j++) St[j] = zero;
#pragma unroll
    for (int kk = 0; kk < 2; kk++) {
#pragma unroll
      for (int j = 0; j < 4; j++) {
        bf16x8 kf = *(const bf16x8*)&Ks[(j * 16 + l15) * 64 + ((kk * 4 + quad + l15) & 7) * 8];
        St[j] = __builtin_amdgcn_mfma_f32_16x16x32_bf16(kf, qa[kk], St[j], 0, 0, 0);
      }
    }

    // in-register softmax over 16 kv values + 2-step cross-quad butterfly
    float mx = St[0][0];
#pragma unroll
    for (int j = 0; j < 4; j++)
#pragma unroll
      for (int r = 0; r < 4; r++) mx = fmaxf(mx, St[j][r]);
    mx = fmaxf(mx, __shfl_xor(mx, 16, 64));
    mx = fmaxf(mx, __shfl_xor(mx, 32, 64));
    mx *= scale2;
    float mnew = fmaxf(m_i, mx);
    float al = __expf(m_i - mnew);
    m_i = mnew;
    float sum = 0.f;
#pragma unroll
    for (int j = 0; j < 4; j++) {
      float p0 = __expf(fmaf(St[j][0], scale2, -mnew));
      float p1 = __expf(fmaf(St[j][1], scale2, -mnew));
      float p2 = __expf(fmaf(St[j][2], scale2, -mnew));
      float p3 = __expf(fmaf(St[j][3], scale2, -mnew));
      sum += (p0 + p1) + (p2 + p3);
      // P[q=w*16+l15][kv=j*16+quad*4 .. +4]
      *(uint2*)&Ps[(w * 16 + l15) * 72 + j * 16 + quad * 4] =
          make_uint2(pk2bf(p0, p1), pk2bf(p2, p3));
    }
    sum += __shfl_xor(sum, 16, 64);
    sum += __shfl_xor(sum, 32, 64);
    l_i = l_i * al + sum;

    // broadcast alpha from lane-dim (l15=q-row) to reg-dim (q-row=quad*4+r)
    float a0 = __shfl(al, quad * 20 + 0, 64);
    float a1 = __shfl(al, quad * 20 + 1, 64);
    float a2 = __shfl(al, quad * 20 + 2, 64);
    float a3 = __shfl(al, quad * 20 + 3, 64);
#pragma unroll
    for (int d = 0; d < 4; d++) {
      O[d][0] *= a0; O[d][1] *= a1; O[d][2] *= a2; O[d][3] *= a3;
    }
    __asm__ __volatile__("s_waitcnt lgkmcnt(0)" ::: "memory");
#pragma unroll
    for (int kk = 0; kk < 2; kk++) {
      bf16x8 pa = *(const bf16x8*)&Ps[(w * 16 + l15) * 72 + kk * 32 + quad * 8];
#pragma unroll
      for (int d = 0; d < 4; d++) {
        bf16x8 vf = *(const bf16x8*)&Vs[(d * 16 + l15) * 64 + ((kk * 4 + quad + l15) & 7) * 8];
        O[d] = __builtin_amdgcn_mfma_f32_16x16x32_bf16(pa, vf, O[d], 0, 0, 0);
      }
    }
    __syncthreads();
  }

  // move m/l into reg-dim rows (q-row = quad*4 + r)
  float l0 = __shfl(l_i, quad * 20 + 0, 64);
  float l1 = __shfl(l_i, quad * 20 + 1, 64);
  float l2 = __shfl(l_i, quad * 20 + 2, 64);
  float l3 = __shfl(l_i, quad * 20 + 3, 64);

  if (nsplit == 1) {
    float inv0 = 1.f / l0, inv1 = 1.f / l1, inv2 = 1.f / l2, inv3 = 1.f / l3;
    u16* Ob = Out + ((size_t)(b * 256 + qt * 64 + w * 16 + quad * 4)) * 768 + h * 64 + l15;
#pragma unroll
    for (int d = 0; d < 4; d++) {
      Ob[(size_t)0 * 768 + d * 16] = f2bf(O[d][0] * inv0);
      Ob[(size_t)1 * 768 + d * 16] = f2bf(O[d][1] * inv1);
      Ob[(size_t)2 * 768 + d * 16] = f2bf(O[d][2] * inv2);
      Ob[(size_t)3 * 768 + d * 16] = f2bf(O[d][3] * inv3);
    }
  } else {
    float m0 = __shfl(m_i, quad * 20 + 0, 64);
    float m1 = __shfl(m_i, quad * 20 + 1, 64);
    float m2 = __shfl(m_i, quad * 20 + 2, 64);
    float m3 = __shfl(m_i, quad * 20 + 3, 64);
    u16* Pb = Part + ((size_t)(bh * 4 + qt) * nsplit + split) * 4096;
    int rowb = w * 16 + quad * 4;
#pragma unroll
    for (int d = 0; d < 4; d++) {
      Pb[(rowb + 0) * 64 + d * 16 + l15] = f2bf(O[d][0]);
      Pb[(rowb + 1) * 64 + d * 16 + l15] = f2bf(O[d][1]);
      Pb[(rowb + 2) * 64 + d * 16 + l15] = f2bf(O[d][2]);
      Pb[(rowb + 3) * 64 + d * 16 + l15] = f2bf(O[d][3]);
    }
    if (l15 == 0) {
      float* MlB = Ml + ((size_t)(bh * 4 + qt) * nsplit + split) * 128;
      MlB[rowb + 0] = m0; MlB[rowb + 1] = m1; MlB[rowb + 2] = m2; MlB[rowb + 3] = m3;
      MlB[64 + rowb + 0] = l0; MlB[64 + rowb + 1] = l1;
      MlB[64 + rowb + 2] = l2; MlB[64 + rowb + 3] = l3;
    }
  }
}

// ---------------- split-KV reduce ----------------
__global__ __launch_bounds__(256) void freduce_kernel(
    const u16* __restrict__ Part, const float* __restrict__ Ml,
    u16* __restrict__ Out, int nsplit) {
  int bid = blockIdx.x;
  int qt = bid & 3, bh = bid >> 2;
  int h = bh % 12, b = bh / 12;
  int tid = threadIdx.x;
  int r = tid >> 2, dc = tid & 3;
  const float* mlb = Ml + (size_t)(bh * 4 + qt) * nsplit * 128;
  float M = -1e30f;
  for (int s = 0; s < nsplit; s++) M = fmaxf(M, mlb[s * 128 + r]);
  float L = 0.f;
  float accv[16];
#pragma unroll
  for (int i = 0; i < 16; i++) accv[i] = 0.f;
  const u16* pb = Part + (size_t)(bh * 4 + qt) * nsplit * 4096 + r * 64 + dc * 16;
  for (int s = 0; s < nsplit; s++) {
    float wgt = __expf(mlb[s * 128 + r] - M);
    L += wgt * mlb[s * 128 + 64 + r];
    u16 tmp[16];
    *(uint4*)tmp = *(const uint4*)(pb + s * 4096);
    *(uint4*)(tmp + 8) = *(const uint4*)(pb + s * 4096 + 8);
#pragma unroll
    for (int i = 0; i < 16; i++) accv[i] += wgt * bf2f(tmp[i]);
  }
  float inv = 1.f / L;
  unsigned ot[8];
#pragma unroll
  for (int i = 0; i < 8; i++)
    ot[i] = pk2bf(accv[2 * i] * inv, accv[2 * i + 1] * inv);
  u16* ob = Out + ((size_t)(b * 256 + qt * 64 + r)) * 768 + h * 64 + dc * 16;
  *(uint4*)ob = *(uint4*)ot;
  *(uint4*)(ob + 8) = *(uint4*)(ot + 4);
}

// ---------------- LayerNorm ----------------
__global__ __launch_bounds__(256) void ln_kernel(const float* __restrict__ X,
                                                 const float* __restrict__ sc,
                                                 const float* __restrict__ bi,
                                                 u16* __restrict__ Hout) {
  int row = blockIdx.x;
  int tid = threadIdx.x;
  const float* x = X + (size_t)row * 768;
  float v0 = x[tid], v1 = x[tid + 256], v2 = x[tid + 512];
  float s = v0 + v1 + v2;
  float q = v0 * v0 + v1 * v1 + v2 * v2;
#pragma unroll
  for (int m = 1; m < 64; m <<= 1) {
    s += __shfl_xor(s, m, 64);
    q += __shfl_xor(q, m, 64);
  }
  __shared__ float rs[4], rq[4];
  if ((tid & 63) == 0) { rs[tid >> 6] = s; rq[tid >> 6] = q; }
  __syncthreads();
  s = rs[0] + rs[1] + rs[2] + rs[3];
  q = rq[0] + rq[1] + rq[2] + rq[3];
  float mu = s * (1.f / 768.f);
  float var = q * (1.f / 768.f) - mu * mu;
  float rstd = rsqrtf(var + 1e-5f);
  u16* ho = Hout + (size_t)row * 768;
  ho[tid]       = f2bf((v0 - mu) * rstd * sc[tid]       + bi[tid]);
  ho[tid + 256] = f2bf((v1 - mu) * rstd * sc[tid + 256] + bi[tid + 256]);
  ho[tid + 512] = f2bf((v2 - mu) * rstd * sc[tid + 512] + bi[tid + 512]);
}

__global__ __launch_bounds__(256) void copy4_kernel(const float* __restrict__ src,
                                                    float* __restrict__ dst, int n4) {
  int i = blockIdx.x * 256 + threadIdx.x;
  if (i < n4) ((float4*)dst)[i] = ((const float4*)src)[i];
}

// =====================================================================
extern "C" void kernel_launch(void* const* d_in, const int* in_sizes, int n_in,
                              void* d_out, int out_size, void* d_ws, size_t ws_size,
                              hipStream_t stream) {
  const float* pc        = (const float*)d_in[0];
  const float* feats     = (const float*)d_in[1];
  const float* query     = (const float*)d_in[2];
  const float* in_W      = (const float*)d_in[3];
  const float* in_b      = (const float*)d_in[4];
  const float* ca_qkv_W  = (const float*)d_in[5];
  const float* ca_qkv_b  = (const float*)d_in[6];
  const float* ca_proj_W = (const float*)d_in[7];
  const float* ca_proj_b = (const float*)d_in[8];
  const float* ln1_s     = (const float*)d_in[9];
  const float* ln1_b     = (const float*)d_in[10];
  const float* qkv_W     = (const float*)d_in[11];
  const float* qkv_b     = (const float*)d_in[12];
  const float* proj_W    = (const float*)d_in[13];
  const float* proj_b    = (const float*)d_in[14];
  const float* ln2_s     = (const float*)d_in[15];
  const float* ln2_b     = (const float*)d_in[16];
  const float* fc_W      = (const float*)d_in[17];
  const float* fc_b      = (const float*)d_in[18];
  const float* fc2_W     = (const float*)d_in[19];
  const float* fc2_b     = (const float*)d_in[20];

  char* base = (char*)d_ws;
  size_t off = 0;
  auto alloc = [&](size_t bytes) -> char* {
    char* p = base + off;
    off += (bytes + 255) & ~(size_t)255;
    return p;
  };

  // ---- fixed region (~25.5 MB) ----
  u16* WqT     = (u16*)alloc(64 * 768 * 2);
  u16* Wquery  = (u16*)alloc(256 * 768 * 2);
  u16* Wcaqkv  = (u16*)alloc(2304 * 768 * 2);
  u16* Wcaproj = (u16*)alloc(768 * 768 * 2);
  u16* Wkp     = (u16*)alloc(1536 * 64 * 2);
  float* bprime = (float*)alloc(1536 * 4);
  u16* qc      = (u16*)alloc(256 * 768 * 2);
  u16* attn    = (u16*)alloc((size_t)2048 * 768 * 2);
  u16* hbuf    = (u16*)alloc((size_t)2048 * 768 * 2);
  char* uni    = alloc(13369344);
  u16* qkvb    = (u16*)uni;
  u16* VtS     = (u16*)(uni + 9437184);
  u16* fc1     = (u16*)uni;
  u16* Part    = (u16*)uni;
  float* Ml    = (float*)(uni + 12582912);

  size_t fixed_end = off;
  const size_t wAllSz = (size_t)8 * (2304 * 768 + 768 * 768 + 2 * 3072 * 768) * 2;
  auto crossSz = [](int cb) {
    return (size_t)cb * 4096 * 64 * 2 + 2 * ((size_t)cb * 4096 * 768 * 2);
  };

  bool allw; int CB;
  if (fixed_end + (wAllSz > crossSz(8) ? wAllSz : crossSz(8)) + 65536 <= ws_size) {
    allw = true;  CB = 8;
  } else if (fixed_end + 14155776 + crossSz(2) + 65536 <= ws_size) {
    allw = false; CB = 2;
  } else {
    allw = false; CB = 1;
  }

  u16 *WqkvB, *WprojB, *WfcB, *Wfc2B, *emb, *kvbK, *VtC;
  if (allw) {
    char* X = base + off;
    WqkvB  = (u16*)X;
    WprojB = WqkvB + (size_t)8 * 2304 * 768;
    WfcB   = WprojB + (size_t)8 * 768 * 768;
    Wfc2B  = WfcB + (size_t)8 * 3072 * 768;
    emb  = (u16*)X;
    kvbK = (u16*)(X + (size_t)CB * 4096 * 64 * 2);
    VtC  = (u16*)(X + (size_t)CB * 4096 * 64 * 2 + (size_t)CB * 4096 * 768 * 2);
  } else {
    WqkvB  = (u16*)alloc(2304 * 768 * 2);
    WprojB = (u16*)alloc(768 * 768 * 2);
    WfcB   = (u16*)alloc(3072 * 768 * 2);
    Wfc2B  = (u16*)alloc((size_t)768 * 3072 * 2);
    emb  = (u16*)alloc((size_t)CB * 4096 * 64 * 2);
    kvbK = (u16*)alloc((size_t)CB * 4096 * 768 * 2);
    VtC  = (u16*)alloc((size_t)CB * 4096 * 768 * 2);
  }

  float* latents = (float*)d_out;
  const float scale2 = 0.125f;

  // --- upfront conversions + fused-weight precompute ---
  {
    int n0 = 256 * 768 / 4, n1 = 2304 * 768 / 4, n2 = 768 * 768 / 4;
    cvt4_kernel<<<(n0 + n1 + n2 + 255) / 256, 256, 0, stream>>>(
        query, Wquery, n0, ca_qkv_W, Wcaqkv, n1, ca_proj_W, Wcaproj, n2,
        nullptr, nullptr, 0);
  }
  pad_inwT_kernel<<<192, 256, 0, stream>>>(in_W, WqT);
  gemm_t<64, 64, 2, 2, 0><<<dim3(24, 1), 256, 0, stream>>>(
      Wcaqkv + (size_t)768 * 768, WqT, nullptr, nullptr, nullptr, Wkp,
      1536, 64, 64, 768, 0, nullptr, 0, 0, 0);
  bprime_kernel<<<384, 256, 0, stream>>>(ca_qkv_W, ca_qkv_b, in_b, bprime);

  // --- latent q projection ---
  gemm_t<64, 64, 2, 2, 0><<<dim3(4, 12), 256, 0, stream>>>(
      Wquery, Wcaqkv, ca_qkv_b, nullptr, nullptr, qc,
      256, 768, 768, 768, 0, nullptr, 0, 0, 0);

  // --- cross-attention, chunked over batches ---
  int nchunk = 8 / CB;
  for (int c = 0; c < nchunk; ++c) {
    int Mc = CB * 4096;
    const float* pc_c = pc + (size_t)c * Mc * 3;
    const float* ft_c = feats + (size_t)c * Mc * 3;
    embed_kernel<<<Mc / 4, 256, 0, stream>>>(pc_c, ft_c, emb);
    gemm_t<128, 128, 2, 2, 1><<<dim3(Mc / 128, 12), 256, 0, stream>>>(
        emb, Wkp, bprime, nullptr, nullptr, kvbK,
        Mc, 1536, 768, 64, 0, VtC, 6, 4096, 12);
    flash_kernel<<<CB * 12 * 16, 256, 0, stream>>>(
        qc, 0L, 768, 64, kvbK, (long)4096 * 768, 768, 64, VtC,
        nullptr, Part, Ml, 4096, 4, 1024, CB * 12, scale2);
    freduce_kernel<<<CB * 48, 256, 0, stream>>>(
        Part, Ml, attn + (size_t)c * CB * 256 * 768, 4);
  }
  gemm_t<64, 64, 2, 2, 0><<<dim3(32, 12), 256, 0, stream>>>(
      attn, Wcaproj, ca_proj_b, nullptr, latents, nullptr,
      2048, 768, 768, 768, 0, nullptr, 0, 0, 0);

  // --- all-layer weight conversion (one sweep) ---
  if (allw) {
    int n0 = 8 * 2304 * 768 / 4, n1 = 8 * 768 * 768 / 4, n2 = 8 * 3072 * 768 / 4;
    cvt4_kernel<<<(n0 + n1 + 2 * n2 + 255) / 256, 256, 0, stream>>>(
        qkv_W, WqkvB, n0, proj_W, WprojB, n1, fc_W, WfcB, n2, fc2_W, Wfc2B, n2);
  }

  // --- transformer layers ---
  for (int l = 0; l < 8; ++l) {
    u16* Wlq  = allw ? WqkvB  + (size_t)l * 2304 * 768 : WqkvB;
    u16* Wlp  = allw ? WprojB + (size_t)l * 768 * 768  : WprojB;
    u16* Wlf  = allw ? WfcB   + (size_t)l * 3072 * 768 : WfcB;
    u16* Wlf2 = allw ? Wfc2B  + (size_t)l * 3072 * 768 : Wfc2B;
    if (!allw) {
      int n0 = 2304 * 768 / 4, n1 = 768 * 768 / 4, n2 = 3072 * 768 / 4;
      cvt4_kernel<<<(n0 + n1 + 2 * n2 + 255) / 256, 256, 0, stream>>>(
          qkv_W + (size_t)l * 2304 * 768, Wlq, n0,
          proj_W + (size_t)l * 768 * 768, Wlp, n1,
          fc_W + (size_t)l * 3072 * 768, Wlf, n2,
          fc2_W + (size_t)l * 768 * 3072, Wlf2, n2);
    }
    ln_kernel<<<2048, 256, 0, stream>>>(latents, ln1_s + l * 768, ln1_b + l * 768, hbuf);
    gemm_t<64, 128, 1, 4, 0><<<dim3(32, 18), 256, 0, stream>>>(
        hbuf, Wlq, qkv_b + l * 2304, nullptr, nullptr, qkvb,
        2048, 2304, 2304, 768, 0, nullptr, 0, 0, 0);
    repack_vt_kernel<<<384, 256, 0, stream>>>(qkvb, (long)256 * 2304, 2304, 128, 192, VtS, 256);
    flash_kernel<<<384, 256, 0, stream>>>(
        qkvb, (long)256 * 2304, 2304, 192, qkvb + 64, (long)256 * 2304, 2304, 192,
        VtS, attn, nullptr, nullptr, 256, 1, 256, 96, scale2);
    gemm_t<64, 64, 2, 2, 0><<<dim3(32, 12), 256, 0, stream>>>(
        attn, Wlp, proj_b + l * 768, latents, latents, nullptr,
        2048, 768, 768, 768, 0, nullptr, 0, 0, 0);
    ln_kernel<<<2048, 256, 0, stream>>>(latents, ln2_s + l * 768, ln2_b + l * 768, hbuf);
    gemm_t<64, 128, 1, 4, 0><<<dim3(32, 24), 256, 0, stream>>>(
        hbuf, Wlf, fc_b + l * 3072, nullptr, nullptr, fc1,
        2048, 3072, 3072, 768, 1, nullptr, 0, 0, 0);
    gemm_t<64, 64, 2, 2, 0><<<dim3(32, 12), 256, 0, stream>>>(
        fc1, Wlf2, fc2_b + l * 768, latents, latents, nullptr,
        2048, 768, 768, 3072, 0, nullptr, 0, 0, 0);
  }

  // --- second output: pc passthrough ---
  copy4_kernel<<<96, 256, 0, stream>>>(pc, (float*)d_out + (size_t)2048 * 768, 98304 / 4);
}

// Round 7
// 1327.259 us; speedup vs baseline: 1.7289x; 1.0271x over previous
//
#include <hip/hip_runtime.h>
#include <stdint.h>

typedef unsigned short u16;
typedef __bf16 bf16x8 __attribute__((ext_vector_type(8)));
typedef float f32x4 __attribute__((ext_vector_type(4)));

#define DEVINL __device__ __forceinline__

DEVINL u16 f2bf(float f) {
  union { float f; unsigned u; } c; c.f = f;
  unsigned u = c.u + 0x7FFFu + ((c.u >> 16) & 1u);
  return (u16)(u >> 16);
}

DEVINL float bf2f(u16 v) {
  union { unsigned u; float f; } c; c.u = (unsigned)v << 16;
  return c.f;
}

// packed fp32x2 -> bf16x2 (HW instruction when available; RNE either way)
DEVINL unsigned pk2bf(float a, float b) {
#if __has_builtin(__builtin_amdgcn_cvt_pk_bf16_f32)
  auto r = __builtin_amdgcn_cvt_pk_bf16_f32(a, b);
  unsigned u;
  __builtin_memcpy(&u, &r, 4);
  return u;
#else
  return (unsigned)f2bf(a) | ((unsigned)f2bf(b) << 16);
#endif
}

DEVINL void gl2lds16(const void* g, void* l) {
  __builtin_amdgcn_global_load_lds(
      (const __attribute__((address_space(1))) unsigned int*)g,
      (__attribute__((address_space(3))) unsigned int*)l, 16, 0, 0);
}

// ---------------- fused 4-segment fp32 -> bf16 conversion ----------------
__global__ __launch_bounds__(256) void cvt4_kernel(
    const float* __restrict__ s0, u16* __restrict__ d0, int n0,
    const float* __restrict__ s1, u16* __restrict__ d1, int n1,
    const float* __restrict__ s2, u16* __restrict__ d2, int n2,
    const float* __restrict__ s3, u16* __restrict__ d3, int n3) {
  int i = blockIdx.x * 256 + threadIdx.x;
  const float* s; u16* d;
  if (i < n0) { s = s0; d = d0; }
  else {
    i -= n0;
    if (i < n1) { s = s1; d = d1; }
    else {
      i -= n1;
      if (i < n2) { s = s2; d = d2; }
      else {
        i -= n2;
        if (i >= n3) return;
        s = s3; d = d3;
      }
    }
  }
  float4 v = ((const float4*)s)[i];
  ((uint2*)d)[i] = make_uint2(pk2bf(v.x, v.y), pk2bf(v.z, v.w));
}

// in_W (768x54) -> bf16 transposed (64x768), rows j>=54 zero
__global__ __launch_bounds__(256) void pad_inwT_kernel(const float* __restrict__ src,
                                                       u16* __restrict__ dst) {
  int t = blockIdx.x * 256 + threadIdx.x;  // 64*768
  if (t >= 64 * 768) return;
  int j = t / 768, o = t - j * 768;
  dst[t] = (j < 54) ? f2bf(src[o * 54 + j]) : (u16)0;
}

// b'[m] = sum_o ca_qkv_W[768+m][o] * in_b[o] + ca_qkv_b[768+m]
__global__ __launch_bounds__(256) void bprime_kernel(const float* __restrict__ caW,
                                                     const float* __restrict__ caB,
                                                     const float* __restrict__ inb,
                                                     float* __restrict__ bp) {
  int w = threadIdx.x >> 6, lane = threadIdx.x & 63;
  int m = blockIdx.x * 4 + w;
  const float* row = caW + (size_t)(768 + m) * 768;
  float s = 0.f;
#pragma unroll
  for (int k = 0; k < 12; k++) s += row[lane + k * 64] * inb[lane + k * 64];
#pragma unroll
  for (int msk = 32; msk >= 1; msk >>= 1) s += __shfl_xor(s, msk, 64);
  if (lane == 0) bp[m] = s + caB[768 + m];
}

// ---------------- fourier embed ----------------
__global__ __launch_bounds__(256) void embed_kernel(const float* __restrict__ pc,
                                                    const float* __restrict__ feats,
                                                    u16* __restrict__ emb) {
  int t = blockIdx.x * 256 + threadIdx.x;
  int p = t >> 6, c = t & 63;
  float v = 0.f;
  if (c < 3) {
    v = pc[p * 3 + c];
  } else if (c < 27) {
    int i = c - 3;
    float f = (float)(1 << (i & 7));
    v = sinf(pc[p * 3 + (i >> 3)] * f);
  } else if (c < 51) {
    int i = c - 27;
    float f = (float)(1 << (i & 7));
    v = cosf(pc[p * 3 + (i >> 3)] * f);
  } else if (c < 54) {
    v = feats[p * 3 + (c - 51)];
  }
  emb[t] = f2bf(v);
}

// ---------------- templated GEMM ----------------
// MODE 0: all tiles normal (operand-swapped MFMA, vectorized epilogue).
// MODE 1: y>=vy -> V transposed into vt[b*768+(n-vy*TN)][skvt] (cross KV, TN=128).
// MODE 2: y%3==2 -> V of head y/3 transposed into vt[(b*12+h)*64+d][skvt] (qkv, TN=64).
template <int TM, int TN, int WR, int WC, int MODE>
__global__ __launch_bounds__(256) void gemm_t(
    const u16* __restrict__ A, const u16* __restrict__ Bw,
    const float* __restrict__ bias, const float* __restrict__ resid,
    float* __restrict__ outF, u16* __restrict__ outB,
    int M, int N, int Nout, int K, int gelu,
    u16* __restrict__ vt, int vy, int skvt, int bsh) {
  constexpr int IM = TM / WR / 16;
  constexpr int IN = TN / WC / 16;
  __shared__ u16 As[TM * 32];
  __shared__ u16 Bs[TN * 32];
  const int tid = threadIdx.x;
  const int lane = tid & 63, w = tid >> 6;
  const int l15 = lane & 15, quad = lane >> 4;
  const int mblk = blockIdx.x * TM, nblk = blockIdx.y * TN;
  const int wm = (w % WR) * (TM / WR);
  const int wn = (w / WR) * (TN / WC);

  f32x4 acc[IM][IN];
#pragma unroll
  for (int i = 0; i < IM; i++)
#pragma unroll
    for (int j = 0; j < IN; j++) acc[i][j] = f32x4{0.f, 0.f, 0.f, 0.f};

  bool tv = false;
  if (MODE == 1) tv = ((int)blockIdx.y >= vy);
  if (MODE == 2) tv = ((int)(blockIdx.y % 3) == 2);

  if (!tv) {
    for (int k0 = 0; k0 < K; k0 += 32) {
#pragma unroll
      for (int s = tid; s < TM * 4; s += 256) {
        int row = s >> 2, c8 = (s & 3) << 3;
        gl2lds16(A + (size_t)(mblk + row) * K + (k0 + c8), &As[s * 8]);
      }
#pragma unroll
      for (int s = tid; s < TN * 4; s += 256) {
        int row = s >> 2, c8 = (s & 3) << 3;
        gl2lds16(Bw + (size_t)(nblk + row) * K + (k0 + c8), &Bs[s * 8]);
      }
      __syncthreads();
      bf16x8 af[IM], bfr[IN];
#pragma unroll
      for (int i = 0; i < IM; i++)
        af[i] = *(const bf16x8*)&As[(wm + i * 16 + l15) * 32 + quad * 8];
#pragma unroll
      for (int j = 0; j < IN; j++)
        bfr[j] = *(const bf16x8*)&Bs[(wn + j * 16 + l15) * 32 + quad * 8];
#pragma unroll
      for (int i = 0; i < IM; i++)
#pragma unroll
        for (int j = 0; j < IN; j++)
          acc[i][j] = __builtin_amdgcn_mfma_f32_16x16x32_bf16(bfr[j], af[i], acc[i][j], 0, 0, 0);
      __syncthreads();
    }
#pragma unroll
    for (int i = 0; i < IM; i++) {
      int m = mblk + wm + i * 16 + l15;
#pragma unroll
      for (int j = 0; j < IN; j++) {
        int n0 = nblk + wn + j * 16 + quad * 4;
        float4 bv = bias ? *(const float4*)&bias[n0] : make_float4(0.f, 0.f, 0.f, 0.f);
        float v0 = acc[i][j][0] + bv.x;
        float v1 = acc[i][j][1] + bv.y;
        float v2 = acc[i][j][2] + bv.z;
        float v3 = acc[i][j][3] + bv.w;
        if (gelu) {
          v0 = 0.5f * v0 * (1.0f + erff(v0 * 0.70710678118f));
          v1 = 0.5f * v1 * (1.0f + erff(v1 * 0.70710678118f));
          v2 = 0.5f * v2 * (1.0f + erff(v2 * 0.70710678118f));
          v3 = 0.5f * v3 * (1.0f + erff(v3 * 0.70710678118f));
        }
        size_t idx = (size_t)m * Nout + n0;
        if (resid) {
          float4 rv = *(const float4*)&resid[idx];
          v0 += rv.x; v1 += rv.y; v2 += rv.z; v3 += rv.w;
        }
        if (outF) {
          float4 ov = {v0, v1, v2, v3};
          *(float4*)&outF[idx] = ov;
        }
        if (outB) {
          *(uint2*)&outB[idx] = make_uint2(pk2bf(v0, v1), pk2bf(v2, v3));
        }
      }
    }
  } else {
    for (int k0 = 0; k0 < K; k0 += 32) {
#pragma unroll
      for (int s = tid; s < TM * 4; s += 256) {
        int row = s >> 2, c8 = (s & 3) << 3;
        gl2lds16(A + (size_t)(mblk + row) * K + (k0 + c8), &As[s * 8]);
      }
#pragma unroll
      for (int s = tid; s < TN * 4; s += 256) {
        int row = s >> 2, c8 = (s & 3) << 3;
        gl2lds16(Bw + (size_t)(nblk + row) * K + (k0 + c8), &Bs[s * 8]);
      }
      __syncthreads();
      bf16x8 af[IM], bfr[IN];
#pragma unroll
      for (int i = 0; i < IM; i++)
        af[i] = *(const bf16x8*)&As[(wm + i * 16 + l15) * 32 + quad * 8];
#pragma unroll
      for (int j = 0; j < IN; j++)
        bfr[j] = *(const bf16x8*)&Bs[(wn + j * 16 + l15) * 32 + quad * 8];
#pragma unroll
      for (int i = 0; i < IM; i++)
#pragma unroll
        for (int j = 0; j < IN; j++)
          acc[i][j] = __builtin_amdgcn_mfma_f32_16x16x32_bf16(af[i], bfr[j], acc[i][j], 0, 0, 0);
      __syncthreads();
    }
    int msk = (1 << bsh) - 1;
#pragma unroll
    for (int j = 0; j < IN; j++) {
      int n = nblk + wn + j * 16 + l15;
      float bv = bias ? bias[n] : 0.f;
#pragma unroll
      for (int i = 0; i < IM; i++) {
        int m0 = mblk + wm + i * 16 + quad * 4;
        int b = m0 >> bsh;
        int s0 = m0 & msk;
        float v0 = acc[i][j][0] + bv;
        float v1 = acc[i][j][1] + bv;
        float v2 = acc[i][j][2] + bv;
        float v3 = acc[i][j][3] + bv;
        size_t vrow;
        if (MODE == 2) {
          int h = blockIdx.y / 3;
          vrow = (size_t)(b * 12 + h) * 64 + (wn + j * 16 + l15);
        } else {
          vrow = (size_t)b * 768 + (n - vy * TN);
        }
        size_t addr = vrow * skvt + s0;
        *(uint2*)&vt[addr] = make_uint2(pk2bf(v0, v1), pk2bf(v2, v3));
      }
    }
  }
}

// ---------------- flash attention: swapped-S softmax (lane = q-row) ----------------
__global__ __launch_bounds__(256) void flash_kernel(
    const u16* __restrict__ Q, long qb, int qrs, int qhs,
    const u16* __restrict__ Kp, long kb, int krs, int khs,
    const u16* __restrict__ Vt, u16* __restrict__ Out,
    u16* __restrict__ Part, float* __restrict__ Ml,
    int Skv, int nsplit, int kvlen, int nbh, float scale2) {
  __shared__ u16 Qs[64 * 64];
  __shared__ u16 Ks[64 * 64];
  __shared__ u16 Vs[64 * 64];
  __shared__ u16 Ps[64 * 72];

  const int tid = threadIdx.x;
  const int lane = tid & 63, w = tid >> 6;
  const int l15 = lane & 15, quad = lane >> 4;

  int bid = blockIdx.x;
  int grp = nbh * nsplit;
  int qt = bid / grp;
  int rem = bid - qt * grp;
  int bh = rem / nsplit;
  int split = rem - bh * nsplit;
  int h = bh % 12, b = bh / 12;

  const u16* Qbase = Q + (size_t)b * qb + (size_t)(qt * 64) * qrs + h * qhs;
  const u16* Kbase = Kp + (size_t)b * kb + (size_t)h * khs;
  const u16* Vbase = Vt + ((size_t)(b * 12 + h) * 64) * Skv;

#pragma unroll
  for (int p = 0; p < 2; ++p) {
    int slot = tid + p * 256;
    int row = slot >> 3, c = slot & 7;
    int cg = (c - row) & 7;
    gl2lds16(Qbase + (size_t)row * qrs + cg * 8, &Qs[slot * 8]);
  }
  __syncthreads();

  bf16x8 qa[2];
#pragma unroll
  for (int kk = 0; kk < 2; kk++)
    qa[kk] = *(const bf16x8*)&Qs[(w * 16 + l15) * 64 + ((kk * 4 + quad + l15) & 7) * 8];

  f32x4 zero = {0.f, 0.f, 0.f, 0.f};
  f32x4 O[4];
#pragma unroll
  for (int d = 0; d < 4; d++) O[d] = zero;
  float m_i = -1e30f, l_i = 0.f;   // per-lane: q-row = w*16 + l15

  int kt0 = split * kvlen;
  for (int kt = kt0; kt < kt0 + kvlen; kt += 64) {
#pragma unroll
    for (int p = 0; p < 2; ++p) {
      int slot = tid + p * 256;
      int row = slot >> 3, c = slot & 7;
      int cg = (c - row) & 7;
      gl2lds16(Kbase + (size_t)(kt + row) * krs + cg * 8, &Ks[slot * 8]);
      gl2lds16(Vbase + (size_t)row * Skv + kt + cg * 8, &Vs[slot * 8]);
    }
    __syncthreads();

    f32x4 St[4];
#pragma unroll
    for (int j = 0; j < 4; j++) St[j] = zero;
#pragma unroll
    for (int kk = 0; kk < 2; kk++) {
#pragma unroll
      for (int j = 0; j < 4; j++) {
        bf16x8 kf = *(const bf16x8*)&Ks[(j * 16 + l15) * 64 + ((kk * 4 + quad + l15) & 7) * 8];
        St[j] = __builtin_amdgcn_mfma_f32_16x16x32_bf16(kf, qa[kk], St[j], 0, 0, 0);
      }
    }

    float mx = St[0][0];
#pragma unroll
    for (int j = 0; j < 4; j++)
#pragma unroll
      for (int r = 0; r < 4; r++) mx = fmaxf(mx, St[j][r]);
    mx = fmaxf(mx, __shfl_xor(mx, 16, 64));
    mx = fmaxf(mx, __shfl_xor(mx, 32, 64));
    mx *= scale2;
    float mnew = fmaxf(m_i, mx);
    float al = __expf(m_i - mnew);
    m_i = mnew;
    float sum = 0.f;
#pragma unroll
    for (int j = 0; j < 4; j++) {
      float p0 = __expf(fmaf(St[j][0], scale2, -mnew));
      float p1 = __expf(fmaf(St[j][1], scale2, -mnew));
      float p2 = __expf(fmaf(St[j][2], scale2, -mnew));
      float p3 = __expf(fmaf(St[j][3], scale2, -mnew));
      sum += (p0 + p1) + (p2 + p3);
      *(uint2*)&Ps[(w * 16 + l15) * 72 + j * 16 + quad * 4] =
          make_uint2(pk2bf(p0, p1), pk2bf(p2, p3));
    }
    sum += __shfl_xor(sum, 16, 64);
    sum += __shfl_xor(sum, 32, 64);
    l_i = l_i * al + sum;

    float a0 = __shfl(al, quad * 20 + 0, 64);
    float a1 = __shfl(al, quad * 20 + 1, 64);
    float a2 = __shfl(al, quad * 20 + 2, 64);
    float a3 = __shfl(al, quad * 20 + 3, 64);
#pragma unroll
    for (int d = 0; d < 4; d++) {
      O[d][0] *= a0; O[d][1] *= a1; O[d][2] *= a2; O[d][3] *= a3;
    }
    __asm__ __volatile__("s_waitcnt lgkmcnt(0)" ::: "memory");
#pragma unroll
    for (int kk = 0; kk < 2; kk++) {
      bf16x8 pa = *(const bf16x8*)&Ps[(w * 16 + l15) * 72 + kk * 32 + quad * 8];
#pragma unroll
      for (int d = 0; d < 4; d++) {
        bf16x8 vf = *(const bf16x8*)&Vs[(d * 16 + l15) * 64 + ((kk * 4 + quad + l15) & 7) * 8];
        O[d] = __builtin_amdgcn_mfma_f32_16x16x32_bf16(pa, vf, O[d], 0, 0, 0);
      }
    }
    __syncthreads();
  }

  float l0 = __shfl(l_i, quad * 20 + 0, 64);
  float l1 = __shfl(l_i, quad * 20 + 1, 64);
  float l2 = __shfl(l_i, quad * 20 + 2, 64);
  float l3 = __shfl(l_i, quad * 20 + 3, 64);

  if (nsplit == 1) {
    float inv0 = 1.f / l0, inv1 = 1.f / l1, inv2 = 1.f / l2, inv3 = 1.f / l3;
    u16* Ob = Out + ((size_t)(b * 256 + qt * 64 + w * 16 + quad * 4)) * 768 + h * 64 + l15;
#pragma unroll
    for (int d = 0; d < 4; d++) {
      Ob[(size_t)0 * 768 + d * 16] = f2bf(O[d][0] * inv0);
      Ob[(size_t)1 * 768 + d * 16] = f2bf(O[d][1] * inv1);
      Ob[(size_t)2 * 768 + d * 16] = f2bf(O[d][2] * inv2);
      Ob[(size_t)3 * 768 + d * 16] = f2bf(O[d][3] * inv3);
    }
  } else {
    float m0 = __shfl(m_i, quad * 20 + 0, 64);
    float m1 = __shfl(m_i, quad * 20 + 1, 64);
    float m2 = __shfl(m_i, quad * 20 + 2, 64);
    float m3 = __shfl(m_i, quad * 20 + 3, 64);
    u16* Pb = Part + ((size_t)(bh * 4 + qt) * nsplit + split) * 4096;
    int rowb = w * 16 + quad * 4;
#pragma unroll
    for (int d = 0; d < 4; d++) {
      Pb[(rowb + 0) * 64 + d * 16 + l15] = f2bf(O[d][0]);
      Pb[(rowb + 1) * 64 + d * 16 + l15] = f2bf(O[d][1]);
      Pb[(rowb + 2) * 64 + d * 16 + l15] = f2bf(O[d][2]);
      Pb[(rowb + 3) * 64 + d * 16 + l15] = f2bf(O[d][3]);
    }
    if (l15 == 0) {
      float* MlB = Ml + ((size_t)(bh * 4 + qt) * nsplit + split) * 128;
      MlB[rowb + 0] = m0; MlB[rowb + 1] = m1; MlB[rowb + 2] = m2; MlB[rowb + 3] = m3;
      MlB[64 + rowb + 0] = l0; MlB[64 + rowb + 1] = l1;
      MlB[64 + rowb + 2] = l2; MlB[64 + rowb + 3] = l3;
    }
  }
}

// ---------------- split-KV reduce ----------------
__global__ __launch_bounds__(256) void freduce_kernel(
    const u16* __restrict__ Part, const float* __restrict__ Ml,
    u16* __restrict__ Out, int nsplit) {
  int bid = blockIdx.x;
  int qt = bid & 3, bh = bid >> 2;
  int h = bh % 12, b = bh / 12;
  int tid = threadIdx.x;
  int r = tid >> 2, dc = tid & 3;
  const float* mlb = Ml + (size_t)(bh * 4 + qt) * nsplit * 128;
  float M = -1e30f;
  for (int s = 0; s < nsplit; s++) M = fmaxf(M, mlb[s * 128 + r]);
  float L = 0.f;
  float accv[16];
#pragma unroll
  for (int i = 0; i < 16; i++) accv[i] = 0.f;
  const u16* pb = Part + (size_t)(bh * 4 + qt) * nsplit * 4096 + r * 64 + dc * 16;
  for (int s = 0; s < nsplit; s++) {
    float wgt = __expf(mlb[s * 128 + r] - M);
    L += wgt * mlb[s * 128 + 64 + r];
    u16 tmp[16];
    *(uint4*)tmp = *(const uint4*)(pb + s * 4096);
    *(uint4*)(tmp + 8) = *(const uint4*)(pb + s * 4096 + 8);
#pragma unroll
    for (int i = 0; i < 16; i++) accv[i] += wgt * bf2f(tmp[i]);
  }
  float inv = 1.f / L;
  unsigned ot[8];
#pragma unroll
  for (int i = 0; i < 8; i++)
    ot[i] = pk2bf(accv[2 * i] * inv, accv[2 * i + 1] * inv);
  u16* ob = Out + ((size_t)(b * 256 + qt * 64 + r)) * 768 + h * 64 + dc * 16;
  *(uint4*)ob = *(uint4*)ot;
  *(uint4*)(ob + 8) = *(uint4*)(ot + 4);
}

// ---------------- LayerNorm ----------------
__global__ __launch_bounds__(256) void ln_kernel(const float* __restrict__ X,
                                                 const float* __restrict__ sc,
                                                 const float* __restrict__ bi,
                                                 u16* __restrict__ Hout) {
  int row = blockIdx.x;
  int tid = threadIdx.x;
  const float* x = X + (size_t)row * 768;
  float v0 = x[tid], v1 = x[tid + 256], v2 = x[tid + 512];
  float s = v0 + v1 + v2;
  float q = v0 * v0 + v1 * v1 + v2 * v2;
#pragma unroll
  for (int m = 1; m < 64; m <<= 1) {
    s += __shfl_xor(s, m, 64);
    q += __shfl_xor(q, m, 64);
  }
  __shared__ float rs[4], rq[4];
  if ((tid & 63) == 0) { rs[tid >> 6] = s; rq[tid >> 6] = q; }
  __syncthreads();
  s = rs[0] + rs[1] + rs[2] + rs[3];
  q = rq[0] + rq[1] + rq[2] + rq[3];
  float mu = s * (1.f / 768.f);
  float var = q * (1.f / 768.f) - mu * mu;
  float rstd = rsqrtf(var + 1e-5f);
  u16* ho = Hout + (size_t)row * 768;
  ho[tid]       = f2bf((v0 - mu) * rstd * sc[tid]       + bi[tid]);
  ho[tid + 256] = f2bf((v1 - mu) * rstd * sc[tid + 256] + bi[tid + 256]);
  ho[tid + 512] = f2bf((v2 - mu) * rstd * sc[tid + 512] + bi[tid + 512]);
}

__global__ __launch_bounds__(256) void copy4_kernel(const float* __restrict__ src,
                                                    float* __restrict__ dst, int n4) {
  int i = blockIdx.x * 256 + threadIdx.x;
  if (i < n4) ((float4*)dst)[i] = ((const float4*)src)[i];
}

// =====================================================================
extern "C" void kernel_launch(void* const* d_in, const int* in_sizes, int n_in,
                              void* d_out, int out_size, void* d_ws, size_t ws_size,
                              hipStream_t stream) {
  const float* pc        = (const float*)d_in[0];
  const float* feats     = (const float*)d_in[1];
  const float* query     = (const float*)d_in[2];
  const float* in_W      = (const float*)d_in[3];
  const float* in_b      = (const float*)d_in[4];
  const float* ca_qkv_W  = (const float*)d_in[5];
  const float* ca_qkv_b  = (const float*)d_in[6];
  const float* ca_proj_W = (const float*)d_in[7];
  const float* ca_proj_b = (const float*)d_in[8];
  const float* ln1_s     = (const float*)d_in[9];
  const float* ln1_b     = (const float*)d_in[10];
  const float* qkv_W     = (const float*)d_in[11];
  const float* qkv_b     = (const float*)d_in[12];
  const float* proj_W    = (const float*)d_in[13];
  const float* proj_b    = (const float*)d_in[14];
  const float* ln2_s     = (const float*)d_in[15];
  const float* ln2_b     = (const float*)d_in[16];
  const float* fc_W      = (const float*)d_in[17];
  const float* fc_b      = (const float*)d_in[18];
  const float* fc2_W     = (const float*)d_in[19];
  const float* fc2_b     = (const float*)d_in[20];

  char* base = (char*)d_ws;
  size_t off = 0;
  auto alloc = [&](size_t bytes) -> char* {
    char* p = base + off;
    off += (bytes + 255) & ~(size_t)255;
    return p;
  };

  // ---- fixed region ----
  u16* WqT     = (u16*)alloc(64 * 768 * 2);
  u16* Wquery  = (u16*)alloc(256 * 768 * 2);
  u16* Wcaqkv  = (u16*)alloc(2304 * 768 * 2);
  u16* Wcaproj = (u16*)alloc(768 * 768 * 2);
  u16* Wkp     = (u16*)alloc(1536 * 64 * 2);
  float* bprime = (float*)alloc(1536 * 4);
  u16* qc      = (u16*)alloc(256 * 768 * 2);
  u16* attn    = (u16*)alloc((size_t)2048 * 768 * 2);
  u16* hbuf    = (u16*)alloc((size_t)2048 * 768 * 2);
  char* uni    = alloc(13369344);
  u16* qkvb    = (u16*)uni;
  u16* VtS     = (u16*)(uni + 9437184);
  u16* fc1     = (u16*)uni;
  u16* Part    = (u16*)uni;
  float* Ml    = (float*)(uni + 12582912);

  size_t fixed_end = off;
  const size_t wAllSz = (size_t)8 * (2304 * 768 + 768 * 768 + 2 * 3072 * 768) * 2;
  auto crossSz = [](int cb) {
    return (size_t)cb * 4096 * 64 * 2 + 2 * ((size_t)cb * 4096 * 768 * 2);
  };

  bool allw; int CB;
  if (fixed_end + (wAllSz > crossSz(8) ? wAllSz : crossSz(8)) + 65536 <= ws_size) {
    allw = true;  CB = 8;
  } else if (fixed_end + 14155776 + crossSz(2) + 65536 <= ws_size) {
    allw = false; CB = 2;
  } else {
    allw = false; CB = 1;
  }

  u16 *WqkvB, *WprojB, *WfcB, *Wfc2B, *emb, *kvbK, *VtC;
  if (allw) {
    char* X = base + off;
    WqkvB  = (u16*)X;
    WprojB = WqkvB + (size_t)8 * 2304 * 768;
    WfcB   = WprojB + (size_t)8 * 768 * 768;
    Wfc2B  = WfcB + (size_t)8 * 3072 * 768;
    emb  = (u16*)X;
    kvbK = (u16*)(X + (size_t)CB * 4096 * 64 * 2);
    VtC  = (u16*)(X + (size_t)CB * 4096 * 64 * 2 + (size_t)CB * 4096 * 768 * 2);
  } else {
    WqkvB  = (u16*)alloc(2304 * 768 * 2);
    WprojB = (u16*)alloc(768 * 768 * 2);
    WfcB   = (u16*)alloc(3072 * 768 * 2);
    Wfc2B  = (u16*)alloc((size_t)768 * 3072 * 2);
    emb  = (u16*)alloc((size_t)CB * 4096 * 64 * 2);
    kvbK = (u16*)alloc((size_t)CB * 4096 * 768 * 2);
    VtC  = (u16*)alloc((size_t)CB * 4096 * 768 * 2);
  }

  float* latents = (float*)d_out;
  const float scale2 = 0.125f;

  // --- upfront conversions + fused-weight precompute ---
  {
    int n0 = 256 * 768 / 4, n1 = 2304 * 768 / 4, n2 = 768 * 768 / 4;
    cvt4_kernel<<<(n0 + n1 + n2 + 255) / 256, 256, 0, stream>>>(
        query, Wquery, n0, ca_qkv_W, Wcaqkv, n1, ca_proj_W, Wcaproj, n2,
        nullptr, nullptr, 0);
  }
  pad_inwT_kernel<<<192, 256, 0, stream>>>(in_W, WqT);
  gemm_t<64, 64, 2, 2, 0><<<dim3(24, 1), 256, 0, stream>>>(
      Wcaqkv + (size_t)768 * 768, WqT, nullptr, nullptr, nullptr, Wkp,
      1536, 64, 64, 768, 0, nullptr, 0, 0, 0);
  bprime_kernel<<<384, 256, 0, stream>>>(ca_qkv_W, ca_qkv_b, in_b, bprime);

  // --- latent q projection ---
  gemm_t<64, 64, 2, 2, 0><<<dim3(4, 12), 256, 0, stream>>>(
      Wquery, Wcaqkv, ca_qkv_b, nullptr, nullptr, qc,
      256, 768, 768, 768, 0, nullptr, 0, 0, 0);

  // --- cross-attention, chunked over batches ---
  int nchunk = 8 / CB;
  for (int c = 0; c < nchunk; ++c) {
    int Mc = CB * 4096;
    const float* pc_c = pc + (size_t)c * Mc * 3;
    const float* ft_c = feats + (size_t)c * Mc * 3;
    embed_kernel<<<Mc / 4, 256, 0, stream>>>(pc_c, ft_c, emb);
    gemm_t<128, 128, 2, 2, 1><<<dim3(Mc / 128, 12), 256, 0, stream>>>(
        emb, Wkp, bprime, nullptr, nullptr, kvbK,
        Mc, 1536, 768, 64, 0, VtC, 6, 4096, 12);
    flash_kernel<<<CB * 12 * 16, 256, 0, stream>>>(
        qc, 0L, 768, 64, kvbK, (long)4096 * 768, 768, 64, VtC,
        nullptr, Part, Ml, 4096, 4, 1024, CB * 12, scale2);
    freduce_kernel<<<CB * 48, 256, 0, stream>>>(
        Part, Ml, attn + (size_t)c * CB * 256 * 768, 4);
  }
  gemm_t<64, 64, 2, 2, 0><<<dim3(32, 12), 256, 0, stream>>>(
      attn, Wcaproj, ca_proj_b, nullptr, latents, nullptr,
      2048, 768, 768, 768, 0, nullptr, 0, 0, 0);

  // --- all-layer weight conversion (one sweep) ---
  if (allw) {
    int n0 = 8 * 2304 * 768 / 4, n1 = 8 * 768 * 768 / 4, n2 = 8 * 3072 * 768 / 4;
    cvt4_kernel<<<(n0 + n1 + 2 * n2 + 255) / 256, 256, 0, stream>>>(
        qkv_W, WqkvB, n0, proj_W, WprojB, n1, fc_W, WfcB, n2, fc2_W, Wfc2B, n2);
  }

  // --- transformer layers ---
  for (int l = 0; l < 8; ++l) {
    u16* Wlq  = allw ? WqkvB  + (size_t)l * 2304 * 768 : WqkvB;
    u16* Wlp  = allw ? WprojB + (size_t)l * 768 * 768  : WprojB;
    u16* Wlf  = allw ? WfcB   + (size_t)l * 3072 * 768 : WfcB;
    u16* Wlf2 = allw ? Wfc2B  + (size_t)l * 3072 * 768 : Wfc2B;
    if (!allw) {
      int n0 = 2304 * 768 / 4, n1 = 768 * 768 / 4, n2 = 3072 * 768 / 4;
      cvt4_kernel<<<(n0 + n1 + 2 * n2 + 255) / 256, 256, 0, stream>>>(
          qkv_W + (size_t)l * 2304 * 768, Wlq, n0,
          proj_W + (size_t)l * 768 * 768, Wlp, n1,
          fc_W + (size_t)l * 3072 * 768, Wlf, n2,
          fc2_W + (size_t)l * 768 * 3072, Wlf2, n2);
    }
    ln_kernel<<<2048, 256, 0, stream>>>(latents, ln1_s + l * 768, ln1_b + l * 768, hbuf);
    // qkv GEMM with fused V^T write (tiles y%3==2 go straight to VtS)
    gemm_t<64, 64, 2, 2, 2><<<dim3(32, 36), 256, 0, stream>>>(
        hbuf, Wlq, qkv_b + l * 2304, nullptr, nullptr, qkvb,
        2048, 2304, 2304, 768, 0, VtS, 0, 256, 8);
    flash_kernel<<<384, 256, 0, stream>>>(
        qkvb, (long)256 * 2304, 2304, 192, qkvb + 64, (long)256 * 2304, 2304, 192,
        VtS, attn, nullptr, nullptr, 256, 1, 256, 96, scale2);
    gemm_t<64, 64, 2, 2, 0><<<dim3(32, 12), 256, 0, stream>>>(
        attn, Wlp, proj_b + l * 768, latents, latents, nullptr,
        2048, 768, 768, 768, 0, nullptr, 0, 0, 0);
    ln_kernel<<<2048, 256, 0, stream>>>(latents, ln2_s + l * 768, ln2_b + l * 768, hbuf);
    gemm_t<64, 128, 1, 4, 0><<<dim3(32, 24), 256, 0, stream>>>(
        hbuf, Wlf, fc_b + l * 3072, nullptr, nullptr, fc1,
        2048, 3072, 3072, 768, 1, nullptr, 0, 0, 0);
    gemm_t<64, 64, 2, 2, 0><<<dim3(32, 12), 256, 0, stream>>>(
        fc1, Wlf2, fc2_b + l * 768, latents, latents, nullptr,
        2048, 768, 768, 3072, 0, nullptr, 0, 0, 0);
  }

  // --- second output: pc passthrough ---
  copy4_kernel<<<96, 256, 0, stream>>>(pc, (float*)d_out + (size_t)2048 * 768, 98304 / 4);
}